// Round 10
// baseline (111.875 us; speedup 1.0000x reference)
//
#include <hip/hip_runtime.h>
#include <hip/hip_bf16.h>

#define B_ 2
#define T_ 2048
#define C_ 1024
#define NH 16
#define NKV 4
#define HD 64
#define NQKV 1536
#define KVB 64

typedef __attribute__((ext_vector_type(4))) float f32x4;
typedef __attribute__((ext_vector_type(8))) short bf16x8;
typedef __attribute__((ext_vector_type(4))) short bf16x4;

__device__ __forceinline__ unsigned short f2bf(float f) {
  __hip_bfloat16 h = __float2bfloat16(f);
  unsigned short u;
  __builtin_memcpy(&u, &h, 2);
  return u;
}

__device__ __forceinline__ float bf2f(unsigned short u) {
  unsigned v = ((unsigned)u) << 16;
  float f;
  __builtin_memcpy(&f, &v, 4);
  return f;
}

__device__ __forceinline__ void gload16(const void* g, void* l) {
  __builtin_amdgcn_global_load_lds(
      (const __attribute__((address_space(1))) void*)g,
      (__attribute__((address_space(3))) void*)l, 16, 0, 0);
}

__device__ __forceinline__ unsigned cvtpk(float lo, float hi_) {
  unsigned w;
  asm("v_cvt_pk_bf16_f32 %0, %1, %2" : "=v"(w) : "v"(lo), "v"(hi_));
  return w;
}

// ---------------- fused f32 -> bf16 convert for all 5 tensors (1 launch) ----------------
#define NX4  1048576
#define NW4  262144
#define NK4  65536
#define O1 (NX4)
#define O2 (O1 + NW4)
#define O3 (O2 + NK4)
#define O4 (O3 + NK4)
#define OT (O4 + NW4)

__global__ __launch_bounds__(256) void conv_all(
    const float* __restrict__ x, const float* __restrict__ wq, const float* __restrict__ wk,
    const float* __restrict__ wv, const float* __restrict__ wo,
    unsigned short* __restrict__ xb, unsigned short* __restrict__ wqkvb,
    unsigned short* __restrict__ wob) {
  int i = blockIdx.x * blockDim.x + threadIdx.x;
  const int stride = gridDim.x * blockDim.x;
  for (; i < OT; i += stride) {
    const float* src;
    unsigned short* dst;
    int j;
    if (i < O1)      { src = x;  dst = xb;                    j = i; }
    else if (i < O2) { src = wq; dst = wqkvb;                 j = i - O1; }
    else if (i < O3) { src = wk; dst = wqkvb + 1024 * 1024;   j = i - O2; }
    else if (i < O4) { src = wv; dst = wqkvb + 1280 * 1024;   j = i - O3; }
    else             { src = wo; dst = wob;                   j = i - O4; }
    const float4 v = reinterpret_cast<const float4*>(src)[j];
    ushort4 o;
    o.x = f2bf(v.x); o.y = f2bf(v.y); o.z = f2bf(v.z); o.w = f2bf(v.w);
    reinterpret_cast<ushort4*>(dst)[j] = o;
  }
}

// ---------------- GEMM: C[M,N] = A[M,K] * B[N,K]^T  (bf16 in, f32/bf16 out) ----------------
// m97 structure, tiles templated (64x64 -> 4-6 blocks/CU for these small shapes: the
// per-K-step vmcnt(0)+barrier drain is hidden by cross-block TLP, not intra-wave ILP).
// global_load_lds w16 staging; source pre-swizzled col^=(row&7)<<4 (rule 21); ds_read
// applies the same XOR.
#define BK 64

template <int BMT, int BNT, bool OUTBF>
__global__ __launch_bounds__(256) void gemm_bt(const unsigned short* __restrict__ A,
                                               const unsigned short* __restrict__ Bw,
                                               void* __restrict__ Cv, int M, int N, int K) {
  constexpr int MI = BMT / 32;               // 16-row frags per wave
  constexpr int NI = BNT / 32;               // 16-col frags per wave
  __shared__ unsigned short Al[BMT * BK];
  __shared__ unsigned short Bl[BNT * BK];
  const int tid = threadIdx.x;
  const int lane = tid & 63;
  const int wid = tid >> 6;
  const int r = lane & 15, g = lane >> 4;
  const int wm = (wid >> 1) * (BMT / 2), wn = (wid & 1) * (BNT / 2);
  const int bm0 = blockIdx.y * BMT, bn0 = blockIdx.x * BNT;
  const int lrow = lane >> 3;
  const int lcol = ((lane & 7) ^ lrow) * 8;  // pre-swizzled source col
  const unsigned short* Asrc = A + (size_t)(bm0 + wid * (BMT / 4) + lrow) * K + lcol;
  const unsigned short* Bsrc = Bw + (size_t)(bn0 + wid * (BNT / 4) + lrow) * K + lcol;
  const int fsw = (r & 7) << 4;
  const char* Ac = (const char*)Al;
  const char* Bc = (const char*)Bl;
  f32x4 acc[MI][NI] = {};
  for (int k0 = 0; k0 < K; k0 += BK) {
    __syncthreads();
#pragma unroll
    for (int i = 0; i < BMT / 32; ++i)
      gload16(Asrc + (size_t)(i * 8) * K + k0, Al + (wid * (BMT / 4) + i * 8) * BK);
#pragma unroll
    for (int i = 0; i < BNT / 32; ++i)
      gload16(Bsrc + (size_t)(i * 8) * K + k0, Bl + (wid * (BNT / 4) + i * 8) * BK);
    __syncthreads();
    bf16x8 af[MI][2], bfr[NI][2];
#pragma unroll
    for (int mi = 0; mi < MI; ++mi)
#pragma unroll
      for (int s = 0; s < 2; ++s)
        af[mi][s] = *reinterpret_cast<const bf16x8*>(
            Ac + (wm + mi * 16 + r) * 128 + ((s * 64 + g * 16) ^ fsw));
#pragma unroll
    for (int ni = 0; ni < NI; ++ni)
#pragma unroll
      for (int s = 0; s < 2; ++s)
        bfr[ni][s] = *reinterpret_cast<const bf16x8*>(
            Bc + (wn + ni * 16 + r) * 128 + ((s * 64 + g * 16) ^ fsw));
#pragma unroll
    for (int s = 0; s < 2; ++s)
#pragma unroll
      for (int mi = 0; mi < MI; ++mi)
#pragma unroll
        for (int ni = 0; ni < NI; ++ni)
          acc[mi][ni] = __builtin_amdgcn_mfma_f32_16x16x32_bf16(af[mi][s], bfr[ni][s],
                                                                acc[mi][ni], 0, 0, 0);
  }
#pragma unroll
  for (int mi = 0; mi < MI; ++mi)
#pragma unroll
    for (int ni = 0; ni < NI; ++ni) {
      const int row = bm0 + wm + mi * 16 + g * 4;
      const int col = bn0 + wn + ni * 16 + r;
#pragma unroll
      for (int e = 0; e < 4; ++e) {
        if (OUTBF)
          ((unsigned short*)Cv)[(size_t)(row + e) * N + col] = f2bf(acc[mi][ni][e]);
        else
          ((float*)Cv)[(size_t)(row + e) * N + col] = acc[mi][ni][e];
      }
    }
}

// ---------------- postprocess: rotary + rmsnorm on q,k ; gate+ve on v ----------------
__global__ __launch_bounds__(256) void postproc(
    const unsigned short* __restrict__ qkv, const float* __restrict__ x,
    const float* __restrict__ ve, const float* __restrict__ cosb,
    const float* __restrict__ sinb, const float* __restrict__ Wg,
    unsigned short* __restrict__ Qn, unsigned short* __restrict__ Kn,
    unsigned short* __restrict__ Vt) {
  const int tok = blockIdx.x;
  const int b = tok / T_, t = tok % T_;
  const int wid = threadIdx.x >> 6, lane = threadIdx.x & 63;
  const unsigned short* qrow = qkv + (size_t)tok * NQKV;
  const float c = cosb[t * 32 + (lane & 31)];
  const float s = sinb[t * 32 + (lane & 31)];
  for (int u = wid; u < 24; u += 4) {
    if (u < 20) {
      const int off = (u < 16) ? u * 64 : 1024 + (u - 16) * 64;
      float v0 = bf2f(qrow[off + lane]);
      float p = __shfl_xor(v0, 32);
      float rot = (lane < 32) ? (v0 * c + p * s) : (v0 * c - p * s);
      float sq = rot * rot;
#pragma unroll
      for (int m = 1; m < 64; m <<= 1) sq += __shfl_xor(sq, m);
      float outv = rot * rsqrtf(sq * (1.0f / 64.0f) + 1.1920929e-7f) *
                   ((u < 16) ? 0.21640425613334453f : 1.2f);
      if (u < 16)
        Qn[((size_t)(b * NH + u) * T_ + t) * HD + lane] = f2bf(outv);
      else
        Kn[((size_t)(b * NKV + (u - 16)) * T_ + t) * HD + lane] = f2bf(outv);
    } else {
      const int kv = u - 20;
      float dot = 0.f;
#pragma unroll
      for (int i = 0; i < 12; ++i) dot += x[(size_t)tok * C_ + i] * Wg[kv * 12 + i];
      const float gate = 3.0f / (1.0f + __expf(-dot));
      const float vv = bf2f(qrow[1280 + kv * 64 + lane]) +
                       gate * ve[(size_t)tok * (NKV * HD) + kv * 64 + lane];
      Vt[((size_t)(b * NKV + kv) * HD + lane) * T_ + t] = f2bf(vv);
    }
  }
}

// ---------------- flash attention, sliding window, GQA ----------------
// R5-proven structure + T5 setprio around MFMA clusters + cvt_pk P-pack + max3 tree.
__global__ __launch_bounds__(256, 4) void attn_fwd(
    const unsigned short* __restrict__ Qn, const unsigned short* __restrict__ Kn,
    const unsigned short* __restrict__ Vt, unsigned short* __restrict__ Y,
    const int* __restrict__ wlp) {
  __shared__ unsigned short Kl[2][KVB * 64];
  __shared__ unsigned short Vl[2][64 * KVB];
  __shared__ unsigned short Pl[4][16 * 64];
  const int b = blockIdx.z, h = blockIdx.y;
  const int kvh = h >> 2;
  const int tid = threadIdx.x;
  const int wid = tid >> 6, lane = tid & 63;
  const int q0 = (gridDim.x - 1 - blockIdx.x) * 64;   // heavy-first
  const int qs = q0 + wid * 16;
  const int r = lane & 15, g = lane >> 4;
  const int wl = *wlp;
  const unsigned short* Qb = Qn + ((size_t)(b * NH + h) * T_ + qs) * HD;
  const unsigned short* Kb = Kn + (size_t)(b * NKV + kvh) * T_ * HD;
  const unsigned short* Vb = Vt + (size_t)(b * NKV + kvh) * HD * T_;
  const bf16x8 qf0 = *reinterpret_cast<const bf16x8*>(Qb + r * HD + g * 8);
  const bf16x8 qf1 = *reinterpret_cast<const bf16x8*>(Qb + r * HD + 32 + g * 8);
  float mrun = -1e30f, lrun = 0.f;
  f32x4 o[4] = {};
  int slo = q0 - wl; if (slo < 0) slo = 0;
  slo &= ~63;
  const int send = q0 + 63;
  const int srow = tid >> 3;
  const int scolb = (tid & 7) * 16;
  const int sdst = srow * 128 + (scolb ^ ((srow & 7) << 4));
  const unsigned short* Ksrc0 = Kb + (size_t)srow * HD + (scolb >> 1);
  const unsigned short* Ksrc1 = Kb + (size_t)(srow + 32) * HD + (scolb >> 1);
  const unsigned short* Vsrc0 = Vb + (size_t)srow * T_ + (scolb >> 1);
  const unsigned short* Vsrc1 = Vb + (size_t)(srow + 32) * T_ + (scolb >> 1);
  char* Pwb = (char*)Pl[wid];
  const int swz = (r & 7) << 4;
  const int ksw = swz;
  const int q = qs + r;

  bf16x8 ska, skb, sva, svb;
  ska = *reinterpret_cast<const bf16x8*>(Ksrc0 + (size_t)slo * HD);
  skb = *reinterpret_cast<const bf16x8*>(Ksrc1 + (size_t)slo * HD);
  sva = *reinterpret_cast<const bf16x8*>(Vsrc0 + slo);
  svb = *reinterpret_cast<const bf16x8*>(Vsrc1 + slo);
  {
    char* Kd = (char*)Kl[0]; char* Vd = (char*)Vl[0];
    *reinterpret_cast<bf16x8*>(Kd + sdst) = ska;
    *reinterpret_cast<bf16x8*>(Kd + 32 * 128 + sdst) = skb;
    *reinterpret_cast<bf16x8*>(Vd + sdst) = sva;
    *reinterpret_cast<bf16x8*>(Vd + 32 * 128 + sdst) = svb;
  }
  __syncthreads();

  int cur = 0;
  for (int sb = slo; sb <= send; sb += KVB) {
    const bool has_next = (sb + KVB <= send);
    if (has_next) {
      const int nb = sb + KVB;
      ska = *reinterpret_cast<const bf16x8*>(Ksrc0 + (size_t)nb * HD);
      skb = *reinterpret_cast<const bf16x8*>(Ksrc1 + (size_t)nb * HD);
      sva = *reinterpret_cast<const bf16x8*>(Vsrc0 + nb);
      svb = *reinterpret_cast<const bf16x8*>(Vsrc1 + nb);
    }
    if (sb <= qs + 15) {
      const char* Kc = (const char*)Kl[cur];
      const char* Vc = (const char*)Vl[cur];
      float sv[16];
      __builtin_amdgcn_s_setprio(1);
#pragma unroll
      for (int sub = 0; sub < 4; ++sub) {
        const int rowb = (sub * 16 + r) * 128;
        bf16x8 kf0 = *reinterpret_cast<const bf16x8*>(Kc + rowb + ((g * 16) ^ ksw));
        bf16x8 kf1 = *reinterpret_cast<const bf16x8*>(Kc + rowb + ((64 + g * 16) ^ ksw));
        f32x4 z = {};
        z = __builtin_amdgcn_mfma_f32_16x16x32_bf16(kf0, qf0, z, 0, 0, 0);
        z = __builtin_amdgcn_mfma_f32_16x16x32_bf16(kf1, qf1, z, 0, 0, 0);
#pragma unroll
        for (int e = 0; e < 4; ++e) sv[sub * 4 + e] = z[e];
      }
      __builtin_amdgcn_s_setprio(0);
      if (sb + 63 > qs || sb < qs + 15 - wl) {
#pragma unroll
        for (int i = 0; i < 16; ++i) {
          const int s_ = sb + (i >> 2) * 16 + g * 4 + (i & 3);
          const bool ok = (unsigned)(q - s_) <= (unsigned)wl;
          sv[i] = ok ? sv[i] : -__builtin_inff();
        }
      }
      // max-tree (max3-fusable nesting)
      float m0 = fmaxf(fmaxf(sv[0], sv[1]), sv[2]);
      float m1 = fmaxf(fmaxf(sv[3], sv[4]), sv[5]);
      float m2 = fmaxf(fmaxf(sv[6], sv[7]), sv[8]);
      float m3 = fmaxf(fmaxf(sv[9], sv[10]), sv[11]);
      float m4 = fmaxf(fmaxf(sv[12], sv[13]), sv[14]);
      float pm = fmaxf(fmaxf(fmaxf(fmaxf(m0, m1), m2), fmaxf(m3, m4)), sv[15]);
      pm = fmaxf(pm, __shfl_xor(pm, 16));
      pm = fmaxf(pm, __shfl_xor(pm, 32));
      if (!__all(pm <= mrun + 8.0f)) {
        const float mnew = fmaxf(mrun, pm);
        const float scl = exp2f(mrun - mnew);
        lrun *= scl;
#pragma unroll
        for (int dt = 0; dt < 4; ++dt)
#pragma unroll
          for (int e = 0; e < 4; ++e) o[dt][e] *= scl;
        mrun = mnew;
      }
      float ps = 0.f;
      float pe[16];
#pragma unroll
      for (int i = 0; i < 16; ++i) {
        pe[i] = exp2f(sv[i] - mrun);
        ps += pe[i];
      }
      ps += __shfl_xor(ps, 16);
      ps += __shfl_xor(ps, 32);
      lrun += ps;
      // pack P via cvt_pk (2 f32 -> 1 u32 of 2 bf16), store swizzled P^T tile
#pragma unroll
      for (int sub = 0; sub < 4; ++sub) {
        unsigned w2[2];
        w2[0] = cvtpk(pe[sub * 4 + 0], pe[sub * 4 + 1]);
        w2[1] = cvtpk(pe[sub * 4 + 2], pe[sub * 4 + 3]);
        bf16x4 w;
        __builtin_memcpy(&w, w2, 8);
        *reinterpret_cast<bf16x4*>(Pwb + ((r * 128 + sub * 32 + g * 8) ^ swz)) = w;
      }
      asm volatile("s_waitcnt lgkmcnt(0)" ::: "memory");
      __builtin_amdgcn_s_setprio(1);
#pragma unroll
      for (int c = 0; c < 2; ++c) {
        const bf16x8 pf = *reinterpret_cast<const bf16x8*>(Pwb + ((r * 128 + c * 64 + g * 16) ^ swz));
#pragma unroll
        for (int dt = 0; dt < 4; ++dt) {
          const int vrow = (dt * 16 + r) * 128;
          const bf16x8 vf = *reinterpret_cast<const bf16x8*>(Vc + vrow + ((c * 64 + g * 16) ^ ksw));
          o[dt] = __builtin_amdgcn_mfma_f32_16x16x32_bf16(vf, pf, o[dt], 0, 0, 0);
        }
      }
      __builtin_amdgcn_s_setprio(0);
    }
    if (has_next) {
      char* Kd = (char*)Kl[cur ^ 1]; char* Vd = (char*)Vl[cur ^ 1];
      *reinterpret_cast<bf16x8*>(Kd + sdst) = ska;
      *reinterpret_cast<bf16x8*>(Kd + 32 * 128 + sdst) = skb;
      *reinterpret_cast<bf16x8*>(Vd + sdst) = sva;
      *reinterpret_cast<bf16x8*>(Vd + 32 * 128 + sdst) = svb;
    }
    __syncthreads();
    cur ^= 1;
  }
  const float inv = 1.0f / lrun;
  unsigned short* Yb = Y + ((size_t)(b * T_) + qs + r) * (NH * HD) + h * HD;
#pragma unroll
  for (int dt = 0; dt < 4; ++dt)
#pragma unroll
    for (int e = 0; e < 4; ++e)
      Yb[dt * 16 + g * 4 + e] = f2bf(o[dt][e] * inv);
}

extern "C" void kernel_launch(void* const* d_in, const int* in_sizes, int n_in,
                              void* d_out, int out_size, void* d_ws, size_t ws_size,
                              hipStream_t stream) {
  const float* x    = (const float*)d_in[0];
  const float* ve   = (const float*)d_in[1];
  const float* cosb = (const float*)d_in[2];
  const float* sinb = (const float*)d_in[3];
  const float* Wq   = (const float*)d_in[4];
  const float* Wk   = (const float*)d_in[5];
  const float* Wv   = (const float*)d_in[6];
  const float* Wo   = (const float*)d_in[7];
  const float* Wg   = (const float*)d_in[8];
  const int*   wlp  = (const int*)d_in[9];

  char* ws = (char*)d_ws;
  unsigned short* xb    = (unsigned short*)ws; ws += (size_t)4096 * 1024 * 2;
  unsigned short* wqkvb = (unsigned short*)ws; ws += (size_t)1536 * 1024 * 2;
  unsigned short* wob   = (unsigned short*)ws; ws += (size_t)1024 * 1024 * 2;
  unsigned short* qkvb  = (unsigned short*)ws; ws += (size_t)4096 * 1536 * 2;
  unsigned short* Qn    = (unsigned short*)ws; ws += (size_t)B_ * NH * T_ * HD * 2;
  unsigned short* Kn    = (unsigned short*)ws; ws += (size_t)B_ * NKV * T_ * HD * 2;
  unsigned short* Vt    = (unsigned short*)ws; ws += (size_t)B_ * NKV * HD * T_ * 2;
  unsigned short* yb    = (unsigned short*)ws; ws += (size_t)4096 * 1024 * 2;

  conv_all<<<dim3(2048), dim3(256), 0, stream>>>(x, Wq, Wk, Wv, Wo, xb, wqkvb, wob);

  gemm_bt<64, 64, true><<<dim3(NQKV / 64, 4096 / 64), dim3(256), 0, stream>>>(
      xb, wqkvb, (void*)qkvb, 4096, NQKV, 1024);

  postproc<<<dim3(4096), dim3(256), 0, stream>>>(qkvb, x, ve, cosb, sinb, Wg, Qn, Kn, Vt);

  attn_fwd<<<dim3(T_ / 64, NH, B_), dim3(256), 0, stream>>>(Qn, Kn, Vt, yb, wlp);

  gemm_bt<64, 64, false><<<dim3(1024 / 64, 4096 / 64), dim3(256), 0, stream>>>(
      yb, wob, d_out, 4096, 1024, 1024);
}

// Round 11
// 104.356 us; speedup vs baseline: 1.0721x; 1.0721x over previous
//
#include <hip/hip_runtime.h>
#include <hip/hip_bf16.h>

#define B_ 2
#define T_ 2048
#define C_ 1024
#define NH 16
#define NKV 4
#define HD 64
#define NQKV 1536
#define KVB 64

typedef __attribute__((ext_vector_type(4))) float f32x4;
typedef __attribute__((ext_vector_type(8))) short bf16x8;
typedef __attribute__((ext_vector_type(4))) short bf16x4;

__device__ __forceinline__ unsigned short f2bf(float f) {
  __hip_bfloat16 h = __float2bfloat16(f);
  unsigned short u;
  __builtin_memcpy(&u, &h, 2);
  return u;
}

__device__ __forceinline__ float bf2f(unsigned short u) {
  unsigned v = ((unsigned)u) << 16;
  float f;
  __builtin_memcpy(&f, &v, 4);
  return f;
}

__device__ __forceinline__ void gload16(const void* g, void* l) {
  __builtin_amdgcn_global_load_lds(
      (const __attribute__((address_space(1))) void*)g,
      (__attribute__((address_space(3))) void*)l, 16, 0, 0);
}

__device__ __forceinline__ unsigned cvtpk(float lo, float hi_) {
  unsigned w;
  asm("v_cvt_pk_bf16_f32 %0, %1, %2" : "=v"(w) : "v"(lo), "v"(hi_));
  return w;
}

// ---------------- fused f32 -> bf16 convert for all 5 tensors (1 launch) ----------------
#define NX4  1048576
#define NW4  262144
#define NK4  65536
#define O1 (NX4)
#define O2 (O1 + NW4)
#define O3 (O2 + NK4)
#define O4 (O3 + NK4)
#define OT (O4 + NW4)

__global__ __launch_bounds__(256) void conv_all(
    const float* __restrict__ x, const float* __restrict__ wq, const float* __restrict__ wk,
    const float* __restrict__ wv, const float* __restrict__ wo,
    unsigned short* __restrict__ xb, unsigned short* __restrict__ wqkvb,
    unsigned short* __restrict__ wob) {
  int i = blockIdx.x * blockDim.x + threadIdx.x;
  const int stride = gridDim.x * blockDim.x;
  for (; i < OT; i += stride) {
    const float* src;
    unsigned short* dst;
    int j;
    if (i < O1)      { src = x;  dst = xb;                    j = i; }
    else if (i < O2) { src = wq; dst = wqkvb;                 j = i - O1; }
    else if (i < O3) { src = wk; dst = wqkvb + 1024 * 1024;   j = i - O2; }
    else if (i < O4) { src = wv; dst = wqkvb + 1280 * 1024;   j = i - O3; }
    else             { src = wo; dst = wob;                   j = i - O4; }
    const float4 v = reinterpret_cast<const float4*>(src)[j];
    ushort4 o;
    o.x = f2bf(v.x); o.y = f2bf(v.y); o.z = f2bf(v.z); o.w = f2bf(v.w);
    reinterpret_cast<ushort4*>(dst)[j] = o;
  }
}

// ---------------- GEMM: C[M,N] = A[M,K] * B[N,K]^T  (bf16 in, f32/bf16 out) ----------------
// m97 structure. R9-proven config: BM=128, BN=64 (gemm1 768 blocks = 3/CU, gemm2 512 = 2/CU).
// global_load_lds w16 staging; source pre-swizzled col^=(row&7)<<4 (rule 21); ds_read
// applies the same XOR.
#define BK 64

template <int BMT, int BNT, bool OUTBF>
__global__ __launch_bounds__(256) void gemm_bt(const unsigned short* __restrict__ A,
                                               const unsigned short* __restrict__ Bw,
                                               void* __restrict__ Cv, int M, int N, int K) {
  constexpr int MI = BMT / 32;               // 16-row frags per wave
  constexpr int NI = BNT / 32;               // 16-col frags per wave
  __shared__ unsigned short Al[BMT * BK];
  __shared__ unsigned short Bl[BNT * BK];
  const int tid = threadIdx.x;
  const int lane = tid & 63;
  const int wid = tid >> 6;
  const int r = lane & 15, g = lane >> 4;
  const int wm = (wid >> 1) * (BMT / 2), wn = (wid & 1) * (BNT / 2);
  const int bm0 = blockIdx.y * BMT, bn0 = blockIdx.x * BNT;
  const int lrow = lane >> 3;
  const int lcol = ((lane & 7) ^ lrow) * 8;  // pre-swizzled source col
  const unsigned short* Asrc = A + (size_t)(bm0 + wid * (BMT / 4) + lrow) * K + lcol;
  const unsigned short* Bsrc = Bw + (size_t)(bn0 + wid * (BNT / 4) + lrow) * K + lcol;
  const int fsw = (r & 7) << 4;
  const char* Ac = (const char*)Al;
  const char* Bc = (const char*)Bl;
  f32x4 acc[MI][NI] = {};
  for (int k0 = 0; k0 < K; k0 += BK) {
    __syncthreads();
#pragma unroll
    for (int i = 0; i < BMT / 32; ++i)
      gload16(Asrc + (size_t)(i * 8) * K + k0, Al + (wid * (BMT / 4) + i * 8) * BK);
#pragma unroll
    for (int i = 0; i < BNT / 32; ++i)
      gload16(Bsrc + (size_t)(i * 8) * K + k0, Bl + (wid * (BNT / 4) + i * 8) * BK);
    __syncthreads();
    bf16x8 af[MI][2], bfr[NI][2];
#pragma unroll
    for (int mi = 0; mi < MI; ++mi)
#pragma unroll
      for (int s = 0; s < 2; ++s)
        af[mi][s] = *reinterpret_cast<const bf16x8*>(
            Ac + (wm + mi * 16 + r) * 128 + ((s * 64 + g * 16) ^ fsw));
#pragma unroll
    for (int ni = 0; ni < NI; ++ni)
#pragma unroll
      for (int s = 0; s < 2; ++s)
        bfr[ni][s] = *reinterpret_cast<const bf16x8*>(
            Bc + (wn + ni * 16 + r) * 128 + ((s * 64 + g * 16) ^ fsw));
#pragma unroll
    for (int s = 0; s < 2; ++s)
#pragma unroll
      for (int mi = 0; mi < MI; ++mi)
#pragma unroll
        for (int ni = 0; ni < NI; ++ni)
          acc[mi][ni] = __builtin_amdgcn_mfma_f32_16x16x32_bf16(af[mi][s], bfr[ni][s],
                                                                acc[mi][ni], 0, 0, 0);
  }
#pragma unroll
  for (int mi = 0; mi < MI; ++mi)
#pragma unroll
    for (int ni = 0; ni < NI; ++ni) {
      const int row = bm0 + wm + mi * 16 + g * 4;
      const int col = bn0 + wn + ni * 16 + r;
#pragma unroll
      for (int e = 0; e < 4; ++e) {
        if (OUTBF)
          ((unsigned short*)Cv)[(size_t)(row + e) * N + col] = f2bf(acc[mi][ni][e]);
        else
          ((float*)Cv)[(size_t)(row + e) * N + col] = acc[mi][ni][e];
      }
    }
}

// ---------------- postprocess: rotary + rmsnorm on q,k ; gate+ve on v ----------------
__global__ __launch_bounds__(256) void postproc(
    const unsigned short* __restrict__ qkv, const float* __restrict__ x,
    const float* __restrict__ ve, const float* __restrict__ cosb,
    const float* __restrict__ sinb, const float* __restrict__ Wg,
    unsigned short* __restrict__ Qn, unsigned short* __restrict__ Kn,
    unsigned short* __restrict__ Vt) {
  const int tok = blockIdx.x;
  const int b = tok / T_, t = tok % T_;
  const int wid = threadIdx.x >> 6, lane = threadIdx.x & 63;
  const unsigned short* qrow = qkv + (size_t)tok * NQKV;
  const float c = cosb[t * 32 + (lane & 31)];
  const float s = sinb[t * 32 + (lane & 31)];
  for (int u = wid; u < 24; u += 4) {
    if (u < 20) {
      const int off = (u < 16) ? u * 64 : 1024 + (u - 16) * 64;
      float v0 = bf2f(qrow[off + lane]);
      float p = __shfl_xor(v0, 32);
      float rot = (lane < 32) ? (v0 * c + p * s) : (v0 * c - p * s);
      float sq = rot * rot;
#pragma unroll
      for (int m = 1; m < 64; m <<= 1) sq += __shfl_xor(sq, m);
      float outv = rot * rsqrtf(sq * (1.0f / 64.0f) + 1.1920929e-7f) *
                   ((u < 16) ? 0.21640425613334453f : 1.2f);
      if (u < 16)
        Qn[((size_t)(b * NH + u) * T_ + t) * HD + lane] = f2bf(outv);
      else
        Kn[((size_t)(b * NKV + (u - 16)) * T_ + t) * HD + lane] = f2bf(outv);
    } else {
      const int kv = u - 20;
      float dot = 0.f;
#pragma unroll
      for (int i = 0; i < 12; ++i) dot += x[(size_t)tok * C_ + i] * Wg[kv * 12 + i];
      const float gate = 3.0f / (1.0f + __expf(-dot));
      const float vv = bf2f(qrow[1280 + kv * 64 + lane]) +
                       gate * ve[(size_t)tok * (NKV * HD) + kv * 64 + lane];
      Vt[((size_t)(b * NKV + kv) * HD + lane) * T_ + t] = f2bf(vv);
    }
  }
}

// ---------------- flash attention, sliding window, GQA ----------------
// R5 structure + balanced static schedule: all 1024 blocks are co-resident (4/CU);
// CU c hosts flat blocks {c, c+256, c+512, c+768} under round-robin dispatch. Map
// slot s=flat>>8, k=(flat&255)&7 -> q-tile {k, 15-k, 16+k, 31-k}: every co-resident
// quad sums to exactly 51 key-tile units (mean). Bijective; perf-only heuristic.
__global__ __launch_bounds__(256, 4) void attn_fwd(
    const unsigned short* __restrict__ Qn, const unsigned short* __restrict__ Kn,
    const unsigned short* __restrict__ Vt, unsigned short* __restrict__ Y,
    const int* __restrict__ wlp) {
  __shared__ unsigned short Kl[2][KVB * 64];
  __shared__ unsigned short Vl[2][64 * KVB];
  __shared__ unsigned short Pl[4][16 * 64];
  const int flat = blockIdx.x + (blockIdx.y << 5) + (blockIdx.z << 9);
  const int c255 = flat & 255, slot = flat >> 8;
  const int kk = c255 & 7;
  const int hb = c255 >> 3;            // 0..31
  const int h = hb & 15, b = hb >> 4;
  int qt;
  if (slot == 0) qt = kk;
  else if (slot == 1) qt = 15 - kk;
  else if (slot == 2) qt = 16 + kk;
  else qt = 31 - kk;
  const int q0 = qt * 64;
  const int kvh = h >> 2;
  const int tid = threadIdx.x;
  const int wid = tid >> 6, lane = tid & 63;
  const int qs = q0 + wid * 16;
  const int r = lane & 15, g = lane >> 4;
  const int wl = *wlp;
  const unsigned short* Qb = Qn + ((size_t)(b * NH + h) * T_ + qs) * HD;
  const unsigned short* Kb = Kn + (size_t)(b * NKV + kvh) * T_ * HD;
  const unsigned short* Vb = Vt + (size_t)(b * NKV + kvh) * HD * T_;
  const bf16x8 qf0 = *reinterpret_cast<const bf16x8*>(Qb + r * HD + g * 8);
  const bf16x8 qf1 = *reinterpret_cast<const bf16x8*>(Qb + r * HD + 32 + g * 8);
  float mrun = -1e30f, lrun = 0.f;
  f32x4 o[4] = {};
  int slo = q0 - wl; if (slo < 0) slo = 0;
  slo &= ~63;
  const int send = q0 + 63;
  const int srow = tid >> 3;
  const int scolb = (tid & 7) * 16;
  const int sdst = srow * 128 + (scolb ^ ((srow & 7) << 4));
  const unsigned short* Ksrc0 = Kb + (size_t)srow * HD + (scolb >> 1);
  const unsigned short* Ksrc1 = Kb + (size_t)(srow + 32) * HD + (scolb >> 1);
  const unsigned short* Vsrc0 = Vb + (size_t)srow * T_ + (scolb >> 1);
  const unsigned short* Vsrc1 = Vb + (size_t)(srow + 32) * T_ + (scolb >> 1);
  char* Pwb = (char*)Pl[wid];
  const int swz = (r & 7) << 4;
  const int ksw = swz;
  const int q = qs + r;

  bf16x8 ska, skb, sva, svb;
  ska = *reinterpret_cast<const bf16x8*>(Ksrc0 + (size_t)slo * HD);
  skb = *reinterpret_cast<const bf16x8*>(Ksrc1 + (size_t)slo * HD);
  sva = *reinterpret_cast<const bf16x8*>(Vsrc0 + slo);
  svb = *reinterpret_cast<const bf16x8*>(Vsrc1 + slo);
  {
    char* Kd = (char*)Kl[0]; char* Vd = (char*)Vl[0];
    *reinterpret_cast<bf16x8*>(Kd + sdst) = ska;
    *reinterpret_cast<bf16x8*>(Kd + 32 * 128 + sdst) = skb;
    *reinterpret_cast<bf16x8*>(Vd + sdst) = sva;
    *reinterpret_cast<bf16x8*>(Vd + 32 * 128 + sdst) = svb;
  }
  __syncthreads();

  int cur = 0;
  for (int sb = slo; sb <= send; sb += KVB) {
    const bool has_next = (sb + KVB <= send);
    if (has_next) {
      const int nb = sb + KVB;
      ska = *reinterpret_cast<const bf16x8*>(Ksrc0 + (size_t)nb * HD);
      skb = *reinterpret_cast<const bf16x8*>(Ksrc1 + (size_t)nb * HD);
      sva = *reinterpret_cast<const bf16x8*>(Vsrc0 + nb);
      svb = *reinterpret_cast<const bf16x8*>(Vsrc1 + nb);
    }
    if (sb <= qs + 15) {
      const char* Kc = (const char*)Kl[cur];
      const char* Vc = (const char*)Vl[cur];
      float sv[16];
      __builtin_amdgcn_s_setprio(1);
#pragma unroll
      for (int sub = 0; sub < 4; ++sub) {
        const int rowb = (sub * 16 + r) * 128;
        bf16x8 kf0 = *reinterpret_cast<const bf16x8*>(Kc + rowb + ((g * 16) ^ ksw));
        bf16x8 kf1 = *reinterpret_cast<const bf16x8*>(Kc + rowb + ((64 + g * 16) ^ ksw));
        f32x4 z = {};
        z = __builtin_amdgcn_mfma_f32_16x16x32_bf16(kf0, qf0, z, 0, 0, 0);
        z = __builtin_amdgcn_mfma_f32_16x16x32_bf16(kf1, qf1, z, 0, 0, 0);
#pragma unroll
        for (int e = 0; e < 4; ++e) sv[sub * 4 + e] = z[e];
      }
      __builtin_amdgcn_s_setprio(0);
      if (sb + 63 > qs || sb < qs + 15 - wl) {
#pragma unroll
        for (int i = 0; i < 16; ++i) {
          const int s_ = sb + (i >> 2) * 16 + g * 4 + (i & 3);
          const bool ok = (unsigned)(q - s_) <= (unsigned)wl;
          sv[i] = ok ? sv[i] : -__builtin_inff();
        }
      }
      float m0 = fmaxf(fmaxf(sv[0], sv[1]), sv[2]);
      float m1 = fmaxf(fmaxf(sv[3], sv[4]), sv[5]);
      float m2 = fmaxf(fmaxf(sv[6], sv[7]), sv[8]);
      float m3 = fmaxf(fmaxf(sv[9], sv[10]), sv[11]);
      float m4 = fmaxf(fmaxf(sv[12], sv[13]), sv[14]);
      float pm = fmaxf(fmaxf(fmaxf(fmaxf(m0, m1), m2), fmaxf(m3, m4)), sv[15]);
      pm = fmaxf(pm, __shfl_xor(pm, 16));
      pm = fmaxf(pm, __shfl_xor(pm, 32));
      if (!__all(pm <= mrun + 8.0f)) {
        const float mnew = fmaxf(mrun, pm);
        const float scl = exp2f(mrun - mnew);
        lrun *= scl;
#pragma unroll
        for (int dt = 0; dt < 4; ++dt)
#pragma unroll
          for (int e = 0; e < 4; ++e) o[dt][e] *= scl;
        mrun = mnew;
      }
      float ps = 0.f;
      float pe[16];
#pragma unroll
      for (int i = 0; i < 16; ++i) {
        pe[i] = exp2f(sv[i] - mrun);
        ps += pe[i];
      }
      ps += __shfl_xor(ps, 16);
      ps += __shfl_xor(ps, 32);
      lrun += ps;
#pragma unroll
      for (int sub = 0; sub < 4; ++sub) {
        unsigned w2[2];
        w2[0] = cvtpk(pe[sub * 4 + 0], pe[sub * 4 + 1]);
        w2[1] = cvtpk(pe[sub * 4 + 2], pe[sub * 4 + 3]);
        bf16x4 w;
        __builtin_memcpy(&w, w2, 8);
        *reinterpret_cast<bf16x4*>(Pwb + ((r * 128 + sub * 32 + g * 8) ^ swz)) = w;
      }
      asm volatile("s_waitcnt lgkmcnt(0)" ::: "memory");
      __builtin_amdgcn_s_setprio(1);
#pragma unroll
      for (int c = 0; c < 2; ++c) {
        const bf16x8 pf = *reinterpret_cast<const bf16x8*>(Pwb + ((r * 128 + c * 64 + g * 16) ^ swz));
#pragma unroll
        for (int dt = 0; dt < 4; ++dt) {
          const int vrow = (dt * 16 + r) * 128;
          const bf16x8 vf = *reinterpret_cast<const bf16x8*>(Vc + vrow + ((c * 64 + g * 16) ^ ksw));
          o[dt] = __builtin_amdgcn_mfma_f32_16x16x32_bf16(vf, pf, o[dt], 0, 0, 0);
        }
      }
      __builtin_amdgcn_s_setprio(0);
    }
    if (has_next) {
      char* Kd = (char*)Kl[cur ^ 1]; char* Vd = (char*)Vl[cur ^ 1];
      *reinterpret_cast<bf16x8*>(Kd + sdst) = ska;
      *reinterpret_cast<bf16x8*>(Kd + 32 * 128 + sdst) = skb;
      *reinterpret_cast<bf16x8*>(Vd + sdst) = sva;
      *reinterpret_cast<bf16x8*>(Vd + 32 * 128 + sdst) = svb;
    }
    __syncthreads();
    cur ^= 1;
  }
  const float inv = 1.0f / lrun;
  unsigned short* Yb = Y + ((size_t)(b * T_) + qs + r) * (NH * HD) + h * HD;
#pragma unroll
  for (int dt = 0; dt < 4; ++dt)
#pragma unroll
    for (int e = 0; e < 4; ++e)
      Yb[dt * 16 + g * 4 + e] = f2bf(o[dt][e] * inv);
}

extern "C" void kernel_launch(void* const* d_in, const int* in_sizes, int n_in,
                              void* d_out, int out_size, void* d_ws, size_t ws_size,
                              hipStream_t stream) {
  const float* x    = (const float*)d_in[0];
  const float* ve   = (const float*)d_in[1];
  const float* cosb = (const float*)d_in[2];
  const float* sinb = (const float*)d_in[3];
  const float* Wq   = (const float*)d_in[4];
  const float* Wk   = (const float*)d_in[5];
  const float* Wv   = (const float*)d_in[6];
  const float* Wo   = (const float*)d_in[7];
  const float* Wg   = (const float*)d_in[8];
  const int*   wlp  = (const int*)d_in[9];

  char* ws = (char*)d_ws;
  unsigned short* xb    = (unsigned short*)ws; ws += (size_t)4096 * 1024 * 2;
  unsigned short* wqkvb = (unsigned short*)ws; ws += (size_t)1536 * 1024 * 2;
  unsigned short* wob   = (unsigned short*)ws; ws += (size_t)1024 * 1024 * 2;
  unsigned short* qkvb  = (unsigned short*)ws; ws += (size_t)4096 * 1536 * 2;
  unsigned short* Qn    = (unsigned short*)ws; ws += (size_t)B_ * NH * T_ * HD * 2;
  unsigned short* Kn    = (unsigned short*)ws; ws += (size_t)B_ * NKV * T_ * HD * 2;
  unsigned short* Vt    = (unsigned short*)ws; ws += (size_t)B_ * NKV * HD * T_ * 2;
  unsigned short* yb    = (unsigned short*)ws; ws += (size_t)4096 * 1024 * 2;

  conv_all<<<dim3(2048), dim3(256), 0, stream>>>(x, Wq, Wk, Wv, Wo, xb, wqkvb, wob);

  gemm_bt<128, 64, true><<<dim3(NQKV / 64, 4096 / 128), dim3(256), 0, stream>>>(
      xb, wqkvb, (void*)qkvb, 4096, NQKV, 1024);

  postproc<<<dim3(4096), dim3(256), 0, stream>>>(qkvb, x, ve, cosb, sinb, Wg, Qn, Kn, Vt);

  attn_fwd<<<dim3(32, NH, B_), dim3(256), 0, stream>>>(Qn, Kn, Vt, yb, wlp);

  gemm_bt<128, 64, false><<<dim3(1024 / 64, 4096 / 128), dim3(256), 0, stream>>>(
      yb, wob, d_out, 4096, 1024, 1024);
}

// Round 12
// 96.362 us; speedup vs baseline: 1.1610x; 1.0830x over previous
//
#include <hip/hip_runtime.h>
#include <hip/hip_bf16.h>

#define B_ 2
#define T_ 2048
#define C_ 1024
#define NH 16
#define NKV 4
#define HD 64
#define NQKV 1536
#define KVB 64

typedef __attribute__((ext_vector_type(4))) float f32x4;
typedef __attribute__((ext_vector_type(8))) short bf16x8;
typedef __attribute__((ext_vector_type(4))) short bf16x4;

__device__ __forceinline__ unsigned short f2bf(float f) {
  __hip_bfloat16 h = __float2bfloat16(f);
  unsigned short u;
  __builtin_memcpy(&u, &h, 2);
  return u;
}

__device__ __forceinline__ float bf2f(unsigned short u) {
  unsigned v = ((unsigned)u) << 16;
  float f;
  __builtin_memcpy(&f, &v, 4);
  return f;
}

__device__ __forceinline__ void gload16(const void* g, void* l) {
  __builtin_amdgcn_global_load_lds(
      (const __attribute__((address_space(1))) void*)g,
      (__attribute__((address_space(3))) void*)l, 16, 0, 0);
}

__device__ __forceinline__ unsigned cvtpk(float lo, float hi_) {
  unsigned w;
  asm("v_cvt_pk_bf16_f32 %0, %1, %2" : "=v"(w) : "v"(lo), "v"(hi_));
  return w;
}

// ---------------- fused f32 -> bf16 convert for all 5 tensors (1 launch) ----------------
#define NX4  1048576
#define NW4  262144
#define NK4  65536
#define O1 (NX4)
#define O2 (O1 + NW4)
#define O3 (O2 + NK4)
#define O4 (O3 + NK4)
#define OT (O4 + NW4)

__global__ __launch_bounds__(256) void conv_all(
    const float* __restrict__ x, const float* __restrict__ wq, const float* __restrict__ wk,
    const float* __restrict__ wv, const float* __restrict__ wo,
    unsigned short* __restrict__ xb, unsigned short* __restrict__ wqkvb,
    unsigned short* __restrict__ wob) {
  int i = blockIdx.x * blockDim.x + threadIdx.x;
  const int stride = gridDim.x * blockDim.x;
  for (; i < OT; i += stride) {
    const float* src;
    unsigned short* dst;
    int j;
    if (i < O1)      { src = x;  dst = xb;                    j = i; }
    else if (i < O2) { src = wq; dst = wqkvb;                 j = i - O1; }
    else if (i < O3) { src = wk; dst = wqkvb + 1024 * 1024;   j = i - O2; }
    else if (i < O4) { src = wv; dst = wqkvb + 1280 * 1024;   j = i - O3; }
    else             { src = wo; dst = wob;                   j = i - O4; }
    const float4 v = reinterpret_cast<const float4*>(src)[j];
    ushort4 o;
    o.x = f2bf(v.x); o.y = f2bf(v.y); o.z = f2bf(v.z); o.w = f2bf(v.w);
    reinterpret_cast<ushort4*>(dst)[j] = o;
  }
}

// ---------------- GEMM: C[M,N] = A[M,K] * B[N,K]^T  (bf16 in, f32/bf16 out) ----------------
// T3 2-phase: double-buffered LDS; next K-tile's global_load_lds ISSUE before compute of
// current tile; single vmcnt(0)+barrier per step (load latency hides under ds_read+MFMA).
// Source pre-swizzled col^=(row&7)<<4 (rule 21); ds_read applies the same XOR.
#define BK 64

template <int BMT, int BNT, bool OUTBF>
__global__ __launch_bounds__(256) void gemm_bt(const unsigned short* __restrict__ A,
                                               const unsigned short* __restrict__ Bw,
                                               void* __restrict__ Cv, int M, int N, int K) {
  constexpr int MI = BMT / 32;               // 16-row frags per wave
  constexpr int NI = BNT / 32;               // 16-col frags per wave
  __shared__ unsigned short Al[2][BMT * BK];
  __shared__ unsigned short Bl[2][BNT * BK];
  const int tid = threadIdx.x;
  const int lane = tid & 63;
  const int wid = tid >> 6;
  const int r = lane & 15, g = lane >> 4;
  const int wm = (wid >> 1) * (BMT / 2), wn = (wid & 1) * (BNT / 2);
  const int bm0 = blockIdx.y * BMT, bn0 = blockIdx.x * BNT;
  const int lrow = lane >> 3;
  const int lcol = ((lane & 7) ^ lrow) * 8;  // pre-swizzled source col
  const unsigned short* Asrc = A + (size_t)(bm0 + wid * (BMT / 4) + lrow) * K + lcol;
  const unsigned short* Bsrc = Bw + (size_t)(bn0 + wid * (BNT / 4) + lrow) * K + lcol;
  const int fsw = (r & 7) << 4;
  f32x4 acc[MI][NI] = {};

  auto stage = [&](int k0, int buf) {
#pragma unroll
    for (int i = 0; i < BMT / 32; ++i)
      gload16(Asrc + (size_t)(i * 8) * K + k0, Al[buf] + (wid * (BMT / 4) + i * 8) * BK);
#pragma unroll
    for (int i = 0; i < BNT / 32; ++i)
      gload16(Bsrc + (size_t)(i * 8) * K + k0, Bl[buf] + (wid * (BNT / 4) + i * 8) * BK);
  };

  stage(0, 0);
  __syncthreads();                 // vmcnt(0) drained by compiler before barrier
  const int nt = K / BK;
  for (int t = 0; t < nt; ++t) {
    const int cur = t & 1;
    if (t + 1 < nt) stage((t + 1) * BK, cur ^ 1);   // issue-early: hides under compute
    const char* Ac = (const char*)Al[cur];
    const char* Bc = (const char*)Bl[cur];
    bf16x8 af[MI][2], bfr[NI][2];
#pragma unroll
    for (int mi = 0; mi < MI; ++mi)
#pragma unroll
      for (int s = 0; s < 2; ++s)
        af[mi][s] = *reinterpret_cast<const bf16x8*>(
            Ac + (wm + mi * 16 + r) * 128 + ((s * 64 + g * 16) ^ fsw));
#pragma unroll
    for (int ni = 0; ni < NI; ++ni)
#pragma unroll
      for (int s = 0; s < 2; ++s)
        bfr[ni][s] = *reinterpret_cast<const bf16x8*>(
            Bc + (wn + ni * 16 + r) * 128 + ((s * 64 + g * 16) ^ fsw));
#pragma unroll
    for (int s = 0; s < 2; ++s)
#pragma unroll
      for (int mi = 0; mi < MI; ++mi)
#pragma unroll
        for (int ni = 0; ni < NI; ++ni)
          acc[mi][ni] = __builtin_amdgcn_mfma_f32_16x16x32_bf16(af[mi][s], bfr[ni][s],
                                                                acc[mi][ni], 0, 0, 0);
    __syncthreads();               // reads of buf[cur] done; prefetch (cur^1) drained
  }
#pragma unroll
  for (int mi = 0; mi < MI; ++mi)
#pragma unroll
    for (int ni = 0; ni < NI; ++ni) {
      const int row = bm0 + wm + mi * 16 + g * 4;
      const int col = bn0 + wn + ni * 16 + r;
#pragma unroll
      for (int e = 0; e < 4; ++e) {
        if (OUTBF)
          ((unsigned short*)Cv)[(size_t)(row + e) * N + col] = f2bf(acc[mi][ni][e]);
        else
          ((float*)Cv)[(size_t)(row + e) * N + col] = acc[mi][ni][e];
      }
    }
}

// ---------------- postprocess: rotary + rmsnorm on q,k ; gate+ve on v ----------------
__global__ __launch_bounds__(256) void postproc(
    const unsigned short* __restrict__ qkv, const float* __restrict__ x,
    const float* __restrict__ ve, const float* __restrict__ cosb,
    const float* __restrict__ sinb, const float* __restrict__ Wg,
    unsigned short* __restrict__ Qn, unsigned short* __restrict__ Kn,
    unsigned short* __restrict__ Vt) {
  const int tok = blockIdx.x;
  const int b = tok / T_, t = tok % T_;
  const int wid = threadIdx.x >> 6, lane = threadIdx.x & 63;
  const unsigned short* qrow = qkv + (size_t)tok * NQKV;
  const float c = cosb[t * 32 + (lane & 31)];
  const float s = sinb[t * 32 + (lane & 31)];
  for (int u = wid; u < 24; u += 4) {
    if (u < 20) {
      const int off = (u < 16) ? u * 64 : 1024 + (u - 16) * 64;
      float v0 = bf2f(qrow[off + lane]);
      float p = __shfl_xor(v0, 32);
      float rot = (lane < 32) ? (v0 * c + p * s) : (v0 * c - p * s);
      float sq = rot * rot;
#pragma unroll
      for (int m = 1; m < 64; m <<= 1) sq += __shfl_xor(sq, m);
      float outv = rot * rsqrtf(sq * (1.0f / 64.0f) + 1.1920929e-7f) *
                   ((u < 16) ? 0.21640425613334453f : 1.2f);
      if (u < 16)
        Qn[((size_t)(b * NH + u) * T_ + t) * HD + lane] = f2bf(outv);
      else
        Kn[((size_t)(b * NKV + (u - 16)) * T_ + t) * HD + lane] = f2bf(outv);
    } else {
      const int kv = u - 20;
      float dot = 0.f;
#pragma unroll
      for (int i = 0; i < 12; ++i) dot += x[(size_t)tok * C_ + i] * Wg[kv * 12 + i];
      const float gate = 3.0f / (1.0f + __expf(-dot));
      const float vv = bf2f(qrow[1280 + kv * 64 + lane]) +
                       gate * ve[(size_t)tok * (NKV * HD) + kv * 64 + lane];
      Vt[((size_t)(b * NKV + kv) * HD + lane) * T_ + t] = f2bf(vv);
    }
  }
}

// ---------------- flash attention, sliding window, GQA ----------------
// R5 structure + balanced static schedule (R11) + FIXED-SHIFT softmax: scores are
// provably bounded |s| <= 16.62 in log2 units (rms-normed q,k: 9.6*9.6/8*log2e), so
// p = exp2(s - 17) with NO running max, NO rescale (softmax shift-invariance, exact).
// lrun is a per-lane partial sum reduced once in the epilogue.
__global__ __launch_bounds__(256, 4) void attn_fwd(
    const unsigned short* __restrict__ Qn, const unsigned short* __restrict__ Kn,
    const unsigned short* __restrict__ Vt, unsigned short* __restrict__ Y,
    const int* __restrict__ wlp) {
  __shared__ unsigned short Kl[2][KVB * 64];
  __shared__ unsigned short Vl[2][64 * KVB];
  __shared__ unsigned short Pl[4][16 * 64];
  const int flat = blockIdx.x + (blockIdx.y << 5) + (blockIdx.z << 9);
  const int c255 = flat & 255, slot = flat >> 8;
  const int kk = c255 & 7;
  const int hb = c255 >> 3;            // 0..31
  const int h = hb & 15, b = hb >> 4;
  int qt;
  if (slot == 0) qt = kk;
  else if (slot == 1) qt = 15 - kk;
  else if (slot == 2) qt = 16 + kk;
  else qt = 31 - kk;
  const int q0 = qt * 64;
  const int kvh = h >> 2;
  const int tid = threadIdx.x;
  const int wid = tid >> 6, lane = tid & 63;
  const int qs = q0 + wid * 16;
  const int r = lane & 15, g = lane >> 4;
  const int wl = *wlp;
  const unsigned short* Qb = Qn + ((size_t)(b * NH + h) * T_ + qs) * HD;
  const unsigned short* Kb = Kn + (size_t)(b * NKV + kvh) * T_ * HD;
  const unsigned short* Vb = Vt + (size_t)(b * NKV + kvh) * HD * T_;
  const bf16x8 qf0 = *reinterpret_cast<const bf16x8*>(Qb + r * HD + g * 8);
  const bf16x8 qf1 = *reinterpret_cast<const bf16x8*>(Qb + r * HD + 32 + g * 8);
  float lrun = 0.f;
  f32x4 o[4] = {};
  int slo = q0 - wl; if (slo < 0) slo = 0;
  slo &= ~63;
  const int send = q0 + 63;
  const int srow = tid >> 3;
  const int scolb = (tid & 7) * 16;
  const int sdst = srow * 128 + (scolb ^ ((srow & 7) << 4));
  const unsigned short* Ksrc0 = Kb + (size_t)srow * HD + (scolb >> 1);
  const unsigned short* Ksrc1 = Kb + (size_t)(srow + 32) * HD + (scolb >> 1);
  const unsigned short* Vsrc0 = Vb + (size_t)srow * T_ + (scolb >> 1);
  const unsigned short* Vsrc1 = Vb + (size_t)(srow + 32) * T_ + (scolb >> 1);
  char* Pwb = (char*)Pl[wid];
  const int swz = (r & 7) << 4;
  const int ksw = swz;
  const int q = qs + r;

  bf16x8 ska, skb, sva, svb;
  ska = *reinterpret_cast<const bf16x8*>(Ksrc0 + (size_t)slo * HD);
  skb = *reinterpret_cast<const bf16x8*>(Ksrc1 + (size_t)slo * HD);
  sva = *reinterpret_cast<const bf16x8*>(Vsrc0 + slo);
  svb = *reinterpret_cast<const bf16x8*>(Vsrc1 + slo);
  {
    char* Kd = (char*)Kl[0]; char* Vd = (char*)Vl[0];
    *reinterpret_cast<bf16x8*>(Kd + sdst) = ska;
    *reinterpret_cast<bf16x8*>(Kd + 32 * 128 + sdst) = skb;
    *reinterpret_cast<bf16x8*>(Vd + sdst) = sva;
    *reinterpret_cast<bf16x8*>(Vd + 32 * 128 + sdst) = svb;
  }
  __syncthreads();

  int cur = 0;
  for (int sb = slo; sb <= send; sb += KVB) {
    const bool has_next = (sb + KVB <= send);
    if (has_next) {
      const int nb = sb + KVB;
      ska = *reinterpret_cast<const bf16x8*>(Ksrc0 + (size_t)nb * HD);
      skb = *reinterpret_cast<const bf16x8*>(Ksrc1 + (size_t)nb * HD);
      sva = *reinterpret_cast<const bf16x8*>(Vsrc0 + nb);
      svb = *reinterpret_cast<const bf16x8*>(Vsrc1 + nb);
    }
    if (sb <= qs + 15) {
      const char* Kc = (const char*)Kl[cur];
      const char* Vc = (const char*)Vl[cur];
      float sv[16];
      __builtin_amdgcn_s_setprio(1);
#pragma unroll
      for (int sub = 0; sub < 4; ++sub) {
        const int rowb = (sub * 16 + r) * 128;
        bf16x8 kf0 = *reinterpret_cast<const bf16x8*>(Kc + rowb + ((g * 16) ^ ksw));
        bf16x8 kf1 = *reinterpret_cast<const bf16x8*>(Kc + rowb + ((64 + g * 16) ^ ksw));
        f32x4 z = {};
        z = __builtin_amdgcn_mfma_f32_16x16x32_bf16(kf0, qf0, z, 0, 0, 0);
        z = __builtin_amdgcn_mfma_f32_16x16x32_bf16(kf1, qf1, z, 0, 0, 0);
#pragma unroll
        for (int e = 0; e < 4; ++e) sv[sub * 4 + e] = z[e];
      }
      __builtin_amdgcn_s_setprio(0);
      if (sb + 63 > qs || sb < qs + 15 - wl) {
#pragma unroll
        for (int i = 0; i < 16; ++i) {
          const int s_ = sb + (i >> 2) * 16 + g * 4 + (i & 3);
          const bool ok = (unsigned)(q - s_) <= (unsigned)wl;
          sv[i] = ok ? sv[i] : -__builtin_inff();
        }
      }
      // fixed-shift softmax: p = exp2(s - 17); no max tracking, no rescale.
      float pe[16];
      float ps = 0.f;
#pragma unroll
      for (int i = 0; i < 16; ++i) {
        pe[i] = exp2f(sv[i] - 17.0f);
        ps += pe[i];
      }
      lrun += ps;                    // per-lane partial; reduced in epilogue
#pragma unroll
      for (int sub = 0; sub < 4; ++sub) {
        unsigned w2[2];
        w2[0] = cvtpk(pe[sub * 4 + 0], pe[sub * 4 + 1]);
        w2[1] = cvtpk(pe[sub * 4 + 2], pe[sub * 4 + 3]);
        bf16x4 w;
        __builtin_memcpy(&w, w2, 8);
        *reinterpret_cast<bf16x4*>(Pwb + ((r * 128 + sub * 32 + g * 8) ^ swz)) = w;
      }
      asm volatile("s_waitcnt lgkmcnt(0)" ::: "memory");
      __builtin_amdgcn_s_setprio(1);
#pragma unroll
      for (int c = 0; c < 2; ++c) {
        const bf16x8 pf = *reinterpret_cast<const bf16x8*>(Pwb + ((r * 128 + c * 64 + g * 16) ^ swz));
#pragma unroll
        for (int dt = 0; dt < 4; ++dt) {
          const int vrow = (dt * 16 + r) * 128;
          const bf16x8 vf = *reinterpret_cast<const bf16x8*>(Vc + vrow + ((c * 64 + g * 16) ^ ksw));
          o[dt] = __builtin_amdgcn_mfma_f32_16x16x32_bf16(vf, pf, o[dt], 0, 0, 0);
        }
      }
      __builtin_amdgcn_s_setprio(0);
    }
    if (has_next) {
      char* Kd = (char*)Kl[cur ^ 1]; char* Vd = (char*)Vl[cur ^ 1];
      *reinterpret_cast<bf16x8*>(Kd + sdst) = ska;
      *reinterpret_cast<bf16x8*>(Kd + 32 * 128 + sdst) = skb;
      *reinterpret_cast<bf16x8*>(Vd + sdst) = sva;
      *reinterpret_cast<bf16x8*>(Vd + 32 * 128 + sdst) = svb;
    }
    __syncthreads();
    cur ^= 1;
  }
  lrun += __shfl_xor(lrun, 16);
  lrun += __shfl_xor(lrun, 32);
  const float inv = 1.0f / lrun;
  unsigned short* Yb = Y + ((size_t)(b * T_) + qs + r) * (NH * HD) + h * HD;
#pragma unroll
  for (int dt = 0; dt < 4; ++dt)
#pragma unroll
    for (int e = 0; e < 4; ++e)
      Yb[dt * 16 + g * 4 + e] = f2bf(o[dt][e] * inv);
}

extern "C" void kernel_launch(void* const* d_in, const int* in_sizes, int n_in,
                              void* d_out, int out_size, void* d_ws, size_t ws_size,
                              hipStream_t stream) {
  const float* x    = (const float*)d_in[0];
  const float* ve   = (const float*)d_in[1];
  const float* cosb = (const float*)d_in[2];
  const float* sinb = (const float*)d_in[3];
  const float* Wq   = (const float*)d_in[4];
  const float* Wk   = (const float*)d_in[5];
  const float* Wv   = (const float*)d_in[6];
  const float* Wo   = (const float*)d_in[7];
  const float* Wg   = (const float*)d_in[8];
  const int*   wlp  = (const int*)d_in[9];

  char* ws = (char*)d_ws;
  unsigned short* xb    = (unsigned short*)ws; ws += (size_t)4096 * 1024 * 2;
  unsigned short* wqkvb = (unsigned short*)ws; ws += (size_t)1536 * 1024 * 2;
  unsigned short* wob   = (unsigned short*)ws; ws += (size_t)1024 * 1024 * 2;
  unsigned short* qkvb  = (unsigned short*)ws; ws += (size_t)4096 * 1536 * 2;
  unsigned short* Qn    = (unsigned short*)ws; ws += (size_t)B_ * NH * T_ * HD * 2;
  unsigned short* Kn    = (unsigned short*)ws; ws += (size_t)B_ * NKV * T_ * HD * 2;
  unsigned short* Vt    = (unsigned short*)ws; ws += (size_t)B_ * NKV * HD * T_ * 2;
  unsigned short* yb    = (unsigned short*)ws; ws += (size_t)4096 * 1024 * 2;

  conv_all<<<dim3(2048), dim3(256), 0, stream>>>(x, Wq, Wk, Wv, Wo, xb, wqkvb, wob);

  gemm_bt<128, 64, true><<<dim3(NQKV / 64, 4096 / 128), dim3(256), 0, stream>>>(
      xb, wqkvb, (void*)qkvb, 4096, NQKV, 1024);

  postproc<<<dim3(4096), dim3(256), 0, stream>>>(qkvb, x, ve, cosb, sinb, Wg, Qn, Kn, Vt);

  attn_fwd<<<dim3(32, NH, B_), dim3(256), 0, stream>>>(Qn, Kn, Vt, yb, wlp);

  gemm_bt<128, 64, false><<<dim3(1024 / 64, 4096 / 128), dim3(256), 0, stream>>>(
      yb, wob, d_out, 4096, 1024, 1024);
}

// Round 13
// 95.376 us; speedup vs baseline: 1.1730x; 1.0103x over previous
//
#include <hip/hip_runtime.h>
#include <hip/hip_bf16.h>

#define B_ 2
#define T_ 2048
#define C_ 1024
#define NH 16
#define NKV 4
#define HD 64
#define NQKV 1536
#define KVB 64

typedef __attribute__((ext_vector_type(4))) float f32x4;
typedef __attribute__((ext_vector_type(8))) short bf16x8;
typedef __attribute__((ext_vector_type(4))) short bf16x4;

__device__ __forceinline__ unsigned short f2bf(float f) {
  __hip_bfloat16 h = __float2bfloat16(f);
  unsigned short u;
  __builtin_memcpy(&u, &h, 2);
  return u;
}

__device__ __forceinline__ float bf2f(unsigned short u) {
  unsigned v = ((unsigned)u) << 16;
  float f;
  __builtin_memcpy(&f, &v, 4);
  return f;
}

__device__ __forceinline__ void gload16(const void* g, void* l) {
  __builtin_amdgcn_global_load_lds(
      (const __attribute__((address_space(1))) void*)g,
      (__attribute__((address_space(3))) void*)l, 16, 0, 0);
}

__device__ __forceinline__ unsigned cvtpk(float lo, float hi_) {
  unsigned w;
  asm("v_cvt_pk_bf16_f32 %0, %1, %2" : "=v"(w) : "v"(lo), "v"(hi_));
  return w;
}

// ---------------- fused f32 -> bf16 convert for all 5 tensors (1 launch) ----------------
#define NX4  1048576
#define NW4  262144
#define NK4  65536
#define O1 (NX4)
#define O2 (O1 + NW4)
#define O3 (O2 + NK4)
#define O4 (O3 + NK4)
#define OT (O4 + NW4)

__global__ __launch_bounds__(256) void conv_all(
    const float* __restrict__ x, const float* __restrict__ wq, const float* __restrict__ wk,
    const float* __restrict__ wv, const float* __restrict__ wo,
    unsigned short* __restrict__ xb, unsigned short* __restrict__ wqkvb,
    unsigned short* __restrict__ wob) {
  int i = blockIdx.x * blockDim.x + threadIdx.x;
  const int stride = gridDim.x * blockDim.x;
  for (; i < OT; i += stride) {
    const float* src;
    unsigned short* dst;
    int j;
    if (i < O1)      { src = x;  dst = xb;                    j = i; }
    else if (i < O2) { src = wq; dst = wqkvb;                 j = i - O1; }
    else if (i < O3) { src = wk; dst = wqkvb + 1024 * 1024;   j = i - O2; }
    else if (i < O4) { src = wv; dst = wqkvb + 1280 * 1024;   j = i - O3; }
    else             { src = wo; dst = wob;                   j = i - O4; }
    const float4 v = reinterpret_cast<const float4*>(src)[j];
    ushort4 o;
    o.x = f2bf(v.x); o.y = f2bf(v.y); o.z = f2bf(v.z); o.w = f2bf(v.w);
    reinterpret_cast<ushort4*>(dst)[j] = o;
  }
}

// ---------------- GEMM: C[M,N] = A[M,K] * B[N,K]^T  (bf16 in, f32/bf16 out) ----------------
// T3 2-phase: double-buffered LDS; next K-tile's global_load_lds ISSUE before compute of
// current tile; single vmcnt(0)+barrier per step (load latency hides under ds_read+MFMA).
// Source pre-swizzled col^=(row&7)<<4 (rule 21); ds_read applies the same XOR.
#define BK 64

template <int BMT, int BNT, bool OUTBF>
__global__ __launch_bounds__(256) void gemm_bt(const unsigned short* __restrict__ A,
                                               const unsigned short* __restrict__ Bw,
                                               void* __restrict__ Cv, int M, int N, int K) {
  constexpr int MI = BMT / 32;               // 16-row frags per wave
  constexpr int NI = BNT / 32;               // 16-col frags per wave
  __shared__ unsigned short Al[2][BMT * BK];
  __shared__ unsigned short Bl[2][BNT * BK];
  const int tid = threadIdx.x;
  const int lane = tid & 63;
  const int wid = tid >> 6;
  const int r = lane & 15, g = lane >> 4;
  const int wm = (wid >> 1) * (BMT / 2), wn = (wid & 1) * (BNT / 2);
  const int bm0 = blockIdx.y * BMT, bn0 = blockIdx.x * BNT;
  const int lrow = lane >> 3;
  const int lcol = ((lane & 7) ^ lrow) * 8;  // pre-swizzled source col
  const unsigned short* Asrc = A + (size_t)(bm0 + wid * (BMT / 4) + lrow) * K + lcol;
  const unsigned short* Bsrc = Bw + (size_t)(bn0 + wid * (BNT / 4) + lrow) * K + lcol;
  const int fsw = (r & 7) << 4;
  f32x4 acc[MI][NI] = {};

  auto stage = [&](int k0, int buf) {
#pragma unroll
    for (int i = 0; i < BMT / 32; ++i)
      gload16(Asrc + (size_t)(i * 8) * K + k0, Al[buf] + (wid * (BMT / 4) + i * 8) * BK);
#pragma unroll
    for (int i = 0; i < BNT / 32; ++i)
      gload16(Bsrc + (size_t)(i * 8) * K + k0, Bl[buf] + (wid * (BNT / 4) + i * 8) * BK);
  };

  stage(0, 0);
  __syncthreads();                 // vmcnt(0) drained by compiler before barrier
  const int nt = K / BK;
  for (int t = 0; t < nt; ++t) {
    const int cur = t & 1;
    if (t + 1 < nt) stage((t + 1) * BK, cur ^ 1);   // issue-early: hides under compute
    const char* Ac = (const char*)Al[cur];
    const char* Bc = (const char*)Bl[cur];
    bf16x8 af[MI][2], bfr[NI][2];
#pragma unroll
    for (int mi = 0; mi < MI; ++mi)
#pragma unroll
      for (int s = 0; s < 2; ++s)
        af[mi][s] = *reinterpret_cast<const bf16x8*>(
            Ac + (wm + mi * 16 + r) * 128 + ((s * 64 + g * 16) ^ fsw));
#pragma unroll
    for (int ni = 0; ni < NI; ++ni)
#pragma unroll
      for (int s = 0; s < 2; ++s)
        bfr[ni][s] = *reinterpret_cast<const bf16x8*>(
            Bc + (wn + ni * 16 + r) * 128 + ((s * 64 + g * 16) ^ fsw));
#pragma unroll
    for (int s = 0; s < 2; ++s)
#pragma unroll
      for (int mi = 0; mi < MI; ++mi)
#pragma unroll
        for (int ni = 0; ni < NI; ++ni)
          acc[mi][ni] = __builtin_amdgcn_mfma_f32_16x16x32_bf16(af[mi][s], bfr[ni][s],
                                                                acc[mi][ni], 0, 0, 0);
    __syncthreads();               // reads of buf[cur] done; prefetch (cur^1) drained
  }
#pragma unroll
  for (int mi = 0; mi < MI; ++mi)
#pragma unroll
    for (int ni = 0; ni < NI; ++ni) {
      const int row = bm0 + wm + mi * 16 + g * 4;
      const int col = bn0 + wn + ni * 16 + r;
#pragma unroll
      for (int e = 0; e < 4; ++e) {
        if (OUTBF)
          ((unsigned short*)Cv)[(size_t)(row + e) * N + col] = f2bf(acc[mi][ni][e]);
        else
          ((float*)Cv)[(size_t)(row + e) * N + col] = acc[mi][ni][e];
      }
    }
}

// ---------------- postprocess: rotary + rmsnorm on q,k ; gate+ve on v ----------------
__global__ __launch_bounds__(256) void postproc(
    const unsigned short* __restrict__ qkv, const float* __restrict__ x,
    const float* __restrict__ ve, const float* __restrict__ cosb,
    const float* __restrict__ sinb, const float* __restrict__ Wg,
    unsigned short* __restrict__ Qn, unsigned short* __restrict__ Kn,
    unsigned short* __restrict__ Vt) {
  const int tok = blockIdx.x;
  const int b = tok / T_, t = tok % T_;
  const int wid = threadIdx.x >> 6, lane = threadIdx.x & 63;
  const unsigned short* qrow = qkv + (size_t)tok * NQKV;
  const float c = cosb[t * 32 + (lane & 31)];
  const float s = sinb[t * 32 + (lane & 31)];
  for (int u = wid; u < 24; u += 4) {
    if (u < 20) {
      const int off = (u < 16) ? u * 64 : 1024 + (u - 16) * 64;
      float v0 = bf2f(qrow[off + lane]);
      float p = __shfl_xor(v0, 32);
      float rot = (lane < 32) ? (v0 * c + p * s) : (v0 * c - p * s);
      float sq = rot * rot;
#pragma unroll
      for (int m = 1; m < 64; m <<= 1) sq += __shfl_xor(sq, m);
      float outv = rot * rsqrtf(sq * (1.0f / 64.0f) + 1.1920929e-7f) *
                   ((u < 16) ? 0.21640425613334453f : 1.2f);
      if (u < 16)
        Qn[((size_t)(b * NH + u) * T_ + t) * HD + lane] = f2bf(outv);
      else
        Kn[((size_t)(b * NKV + (u - 16)) * T_ + t) * HD + lane] = f2bf(outv);
    } else {
      const int kv = u - 20;
      float dot = 0.f;
#pragma unroll
      for (int i = 0; i < 12; ++i) dot += x[(size_t)tok * C_ + i] * Wg[kv * 12 + i];
      const float gate = 3.0f / (1.0f + __expf(-dot));
      const float vv = bf2f(qrow[1280 + kv * 64 + lane]) +
                       gate * ve[(size_t)tok * (NKV * HD) + kv * 64 + lane];
      Vt[((size_t)(b * NKV + kv) * HD + lane) * T_ + t] = f2bf(vv);
    }
  }
}

// ---------------- flash attention, sliding window, GQA ----------------
// EQUAL-WORK blocks: q-tile qt costs qt+1 key-tiles (qt<16) or 17 (qt>=16). Pairing
// {j, 15-j} gives exactly 17; singles qt>=16 are 17. Grid (24, NH, B) = 768 blocks,
// all EXACTLY 17 tile-units -> 3 blocks/CU co-resident for the whole kernel, no decay.
// Pair blocks run two segments sequentially (LDS pipeline reused; final barrier of a
// segment orders all reads before next prologue's writes).
// Fixed-shift softmax: scores bounded |s|<=16.62 log2-units -> p=exp2(s-17), exact.
__global__ __launch_bounds__(256, 4) void attn_fwd(
    const unsigned short* __restrict__ Qn, const unsigned short* __restrict__ Kn,
    const unsigned short* __restrict__ Vt, unsigned short* __restrict__ Y,
    const int* __restrict__ wlp) {
  __shared__ unsigned short Kl[2][KVB * 64];
  __shared__ unsigned short Vl[2][64 * KVB];
  __shared__ unsigned short Pl[4][16 * 64];
  const int j = blockIdx.x, h = blockIdx.y, b = blockIdx.z;
  const int kvh = h >> 2;
  const int tid = threadIdx.x;
  const int wid = tid >> 6, lane = tid & 63;
  const int r = lane & 15, g = lane >> 4;
  const int wl = *wlp;
  const unsigned short* Kb = Kn + (size_t)(b * NKV + kvh) * T_ * HD;
  const unsigned short* Vb = Vt + (size_t)(b * NKV + kvh) * HD * T_;
  const int srow = tid >> 3;
  const int scolb = (tid & 7) * 16;
  const int sdst = srow * 128 + (scolb ^ ((srow & 7) << 4));
  const unsigned short* Ksrc0 = Kb + (size_t)srow * HD + (scolb >> 1);
  const unsigned short* Ksrc1 = Kb + (size_t)(srow + 32) * HD + (scolb >> 1);
  const unsigned short* Vsrc0 = Vb + (size_t)srow * T_ + (scolb >> 1);
  const unsigned short* Vsrc1 = Vb + (size_t)(srow + 32) * T_ + (scolb >> 1);
  char* Pwb = (char*)Pl[wid];
  const int swz = (r & 7) << 4;
  const int ksw = swz;
  const int nseg = (j < 8) ? 2 : 1;

  for (int seg = 0; seg < nseg; ++seg) {
    const int qt = (j < 8) ? (seg ? 15 - j : j) : j + 8;
    const int q0 = qt * 64;
    const int qs = q0 + wid * 16;
    const int q = qs + r;
    const unsigned short* Qb = Qn + ((size_t)(b * NH + h) * T_ + qs) * HD;
    const bf16x8 qf0 = *reinterpret_cast<const bf16x8*>(Qb + r * HD + g * 8);
    const bf16x8 qf1 = *reinterpret_cast<const bf16x8*>(Qb + r * HD + 32 + g * 8);
    float lrun = 0.f;
    f32x4 o[4] = {};
    int slo = q0 - wl; if (slo < 0) slo = 0;
    slo &= ~63;
    const int send = q0 + 63;

    bf16x8 ska, skb, sva, svb;
    ska = *reinterpret_cast<const bf16x8*>(Ksrc0 + (size_t)slo * HD);
    skb = *reinterpret_cast<const bf16x8*>(Ksrc1 + (size_t)slo * HD);
    sva = *reinterpret_cast<const bf16x8*>(Vsrc0 + slo);
    svb = *reinterpret_cast<const bf16x8*>(Vsrc1 + slo);
    {
      char* Kd = (char*)Kl[0]; char* Vd = (char*)Vl[0];
      *reinterpret_cast<bf16x8*>(Kd + sdst) = ska;
      *reinterpret_cast<bf16x8*>(Kd + 32 * 128 + sdst) = skb;
      *reinterpret_cast<bf16x8*>(Vd + sdst) = sva;
      *reinterpret_cast<bf16x8*>(Vd + 32 * 128 + sdst) = svb;
    }
    __syncthreads();

    int cur = 0;
    for (int sb = slo; sb <= send; sb += KVB) {
      const bool has_next = (sb + KVB <= send);
      if (has_next) {
        const int nb = sb + KVB;
        ska = *reinterpret_cast<const bf16x8*>(Ksrc0 + (size_t)nb * HD);
        skb = *reinterpret_cast<const bf16x8*>(Ksrc1 + (size_t)nb * HD);
        sva = *reinterpret_cast<const bf16x8*>(Vsrc0 + nb);
        svb = *reinterpret_cast<const bf16x8*>(Vsrc1 + nb);
      }
      {
        const char* Kc = (const char*)Kl[cur];
        const char* Vc = (const char*)Vl[cur];
        float sv[16];
        __builtin_amdgcn_s_setprio(1);
#pragma unroll
        for (int sub = 0; sub < 4; ++sub) {
          const int rowb = (sub * 16 + r) * 128;
          bf16x8 kf0 = *reinterpret_cast<const bf16x8*>(Kc + rowb + ((g * 16) ^ ksw));
          bf16x8 kf1 = *reinterpret_cast<const bf16x8*>(Kc + rowb + ((64 + g * 16) ^ ksw));
          f32x4 z = {};
          z = __builtin_amdgcn_mfma_f32_16x16x32_bf16(kf0, qf0, z, 0, 0, 0);
          z = __builtin_amdgcn_mfma_f32_16x16x32_bf16(kf1, qf1, z, 0, 0, 0);
#pragma unroll
          for (int e = 0; e < 4; ++e) sv[sub * 4 + e] = z[e];
        }
        __builtin_amdgcn_s_setprio(0);
        if (sb + 63 > qs || sb < qs + 15 - wl) {
#pragma unroll
          for (int i = 0; i < 16; ++i) {
            const int s_ = sb + (i >> 2) * 16 + g * 4 + (i & 3);
            const bool ok = (unsigned)(q - s_) <= (unsigned)wl;
            sv[i] = ok ? sv[i] : -__builtin_inff();
          }
        }
        // fixed-shift softmax: p = exp2(s - 17); no max tracking, no rescale.
        float pe[16];
        float ps = 0.f;
#pragma unroll
        for (int i = 0; i < 16; ++i) {
          pe[i] = exp2f(sv[i] - 17.0f);
          ps += pe[i];
        }
        lrun += ps;                    // per-lane partial; reduced in epilogue
#pragma unroll
        for (int sub = 0; sub < 4; ++sub) {
          unsigned w2[2];
          w2[0] = cvtpk(pe[sub * 4 + 0], pe[sub * 4 + 1]);
          w2[1] = cvtpk(pe[sub * 4 + 2], pe[sub * 4 + 3]);
          bf16x4 w;
          __builtin_memcpy(&w, w2, 8);
          *reinterpret_cast<bf16x4*>(Pwb + ((r * 128 + sub * 32 + g * 8) ^ swz)) = w;
        }
        asm volatile("s_waitcnt lgkmcnt(0)" ::: "memory");
        __builtin_amdgcn_s_setprio(1);
#pragma unroll
        for (int c = 0; c < 2; ++c) {
          const bf16x8 pf = *reinterpret_cast<const bf16x8*>(Pwb + ((r * 128 + c * 64 + g * 16) ^ swz));
#pragma unroll
          for (int dt = 0; dt < 4; ++dt) {
            const int vrow = (dt * 16 + r) * 128;
            const bf16x8 vf = *reinterpret_cast<const bf16x8*>(Vc + vrow + ((c * 64 + g * 16) ^ ksw));
            o[dt] = __builtin_amdgcn_mfma_f32_16x16x32_bf16(vf, pf, o[dt], 0, 0, 0);
          }
        }
        __builtin_amdgcn_s_setprio(0);
      }
      if (has_next) {
        char* Kd = (char*)Kl[cur ^ 1]; char* Vd = (char*)Vl[cur ^ 1];
        *reinterpret_cast<bf16x8*>(Kd + sdst) = ska;
        *reinterpret_cast<bf16x8*>(Kd + 32 * 128 + sdst) = skb;
        *reinterpret_cast<bf16x8*>(Vd + sdst) = sva;
        *reinterpret_cast<bf16x8*>(Vd + 32 * 128 + sdst) = svb;
      }
      __syncthreads();
      cur ^= 1;
    }
    lrun += __shfl_xor(lrun, 16);
    lrun += __shfl_xor(lrun, 32);
    const float inv = 1.0f / lrun;
    unsigned short* Yb = Y + ((size_t)(b * T_) + qs + r) * (NH * HD) + h * HD;
#pragma unroll
    for (int dt = 0; dt < 4; ++dt)
#pragma unroll
      for (int e = 0; e < 4; ++e)
        Yb[dt * 16 + g * 4 + e] = f2bf(o[dt][e] * inv);
  }
}

extern "C" void kernel_launch(void* const* d_in, const int* in_sizes, int n_in,
                              void* d_out, int out_size, void* d_ws, size_t ws_size,
                              hipStream_t stream) {
  const float* x    = (const float*)d_in[0];
  const float* ve   = (const float*)d_in[1];
  const float* cosb = (const float*)d_in[2];
  const float* sinb = (const float*)d_in[3];
  const float* Wq   = (const float*)d_in[4];
  const float* Wk   = (const float*)d_in[5];
  const float* Wv   = (const float*)d_in[6];
  const float* Wo   = (const float*)d_in[7];
  const float* Wg   = (const float*)d_in[8];
  const int*   wlp  = (const int*)d_in[9];

  char* ws = (char*)d_ws;
  unsigned short* xb    = (unsigned short*)ws; ws += (size_t)4096 * 1024 * 2;
  unsigned short* wqkvb = (unsigned short*)ws; ws += (size_t)1536 * 1024 * 2;
  unsigned short* wob   = (unsigned short*)ws; ws += (size_t)1024 * 1024 * 2;
  unsigned short* qkvb  = (unsigned short*)ws; ws += (size_t)4096 * 1536 * 2;
  unsigned short* Qn    = (unsigned short*)ws; ws += (size_t)B_ * NH * T_ * HD * 2;
  unsigned short* Kn    = (unsigned short*)ws; ws += (size_t)B_ * NKV * T_ * HD * 2;
  unsigned short* Vt    = (unsigned short*)ws; ws += (size_t)B_ * NKV * HD * T_ * 2;
  unsigned short* yb    = (unsigned short*)ws; ws += (size_t)4096 * 1024 * 2;

  conv_all<<<dim3(2048), dim3(256), 0, stream>>>(x, Wq, Wk, Wv, Wo, xb, wqkvb, wob);

  gemm_bt<128, 64, true><<<dim3(NQKV / 64, 4096 / 128), dim3(256), 0, stream>>>(
      xb, wqkvb, (void*)qkvb, 4096, NQKV, 1024);

  postproc<<<dim3(4096), dim3(256), 0, stream>>>(qkvb, x, ve, cosb, sinb, Wg, Qn, Kn, Vt);

  attn_fwd<<<dim3(24, NH, B_), dim3(256), 0, stream>>>(Qn, Kn, Vt, yb, wlp);

  gemm_bt<128, 64, false><<<dim3(1024 / 64, 4096 / 128), dim3(256), 0, stream>>>(
      yb, wob, d_out, 4096, 1024, 1024);
}

// Round 14
// 81.200 us; speedup vs baseline: 1.3778x; 1.1746x over previous
//
#include <hip/hip_runtime.h>
#include <hip/hip_bf16.h>

#define B_ 2
#define T_ 2048
#define C_ 1024
#define NH 16
#define NKV 4
#define HD 64
#define NQKV 1536
#define KVB 64

typedef __attribute__((ext_vector_type(4))) float f32x4;
typedef __attribute__((ext_vector_type(8))) short bf16x8;
typedef __attribute__((ext_vector_type(4))) short bf16x4;

__device__ __forceinline__ unsigned short f2bf(float f) {
  __hip_bfloat16 h = __float2bfloat16(f);
  unsigned short u;
  __builtin_memcpy(&u, &h, 2);
  return u;
}

__device__ __forceinline__ void gload16(const void* g, void* l) {
  __builtin_amdgcn_global_load_lds(
      (const __attribute__((address_space(1))) void*)g,
      (__attribute__((address_space(3))) void*)l, 16, 0, 0);
}

__device__ __forceinline__ unsigned cvtpk(float lo, float hi_) {
  unsigned w;
  asm("v_cvt_pk_bf16_f32 %0, %1, %2" : "=v"(w) : "v"(lo), "v"(hi_));
  return w;
}

// ---------------- fused f32 -> bf16 convert for all 5 tensors (1 launch) ----------------
#define NX4  1048576
#define NW4  262144
#define NK4  65536
#define O1 (NX4)
#define O2 (O1 + NW4)
#define O3 (O2 + NK4)
#define O4 (O3 + NK4)
#define OT (O4 + NW4)

__global__ __launch_bounds__(256) void conv_all(
    const float* __restrict__ x, const float* __restrict__ wq, const float* __restrict__ wk,
    const float* __restrict__ wv, const float* __restrict__ wo,
    unsigned short* __restrict__ xb, unsigned short* __restrict__ wqkvb,
    unsigned short* __restrict__ wob) {
  int i = blockIdx.x * blockDim.x + threadIdx.x;
  const int stride = gridDim.x * blockDim.x;
  for (; i < OT; i += stride) {
    const float* src;
    unsigned short* dst;
    int j;
    if (i < O1)      { src = x;  dst = xb;                    j = i; }
    else if (i < O2) { src = wq; dst = wqkvb;                 j = i - O1; }
    else if (i < O3) { src = wk; dst = wqkvb + 1024 * 1024;   j = i - O2; }
    else if (i < O4) { src = wv; dst = wqkvb + 1280 * 1024;   j = i - O3; }
    else             { src = wo; dst = wob;                   j = i - O4; }
    const float4 v = reinterpret_cast<const float4*>(src)[j];
    ushort4 o;
    o.x = f2bf(v.x); o.y = f2bf(v.y); o.z = f2bf(v.z); o.w = f2bf(v.w);
    reinterpret_cast<ushort4*>(dst)[j] = o;
  }
}

// ------- fused QKV GEMM + rotary/rmsnorm/gate epilogue (replaces gemm1 + postproc) -------
// BM=128, BN=64: each block = 128 tokens x exactly one head (N=1536=24*64). T3 2-phase
// main loop (same as gemm_bt). Epilogue: acc -> LDS f32 [128][65] (padded: stride-64
// would be a 64-way bank conflict) -> 2 threads/token do rotary + rmsnorm (+Q/K scale)
// or gate+ve (V heads; second LDS stage for the [d][t] transposed coalesced store).
#define BK 64

__global__ __launch_bounds__(256) void gemm_qkv(
    const unsigned short* __restrict__ A, const unsigned short* __restrict__ Bw,
    const float* __restrict__ x, const float* __restrict__ ve,
    const float* __restrict__ cosb, const float* __restrict__ sinb,
    const float* __restrict__ Wg,
    unsigned short* __restrict__ Qn, unsigned short* __restrict__ Kn,
    unsigned short* __restrict__ Vt) {
  constexpr int BMT = 128, BNT = 64, MI = 4, NI = 2, K = 1024;
  __shared__ char smem[50176];
  unsigned short* AlB = (unsigned short*)smem;             // 2 x [128*64]
  unsigned short* BlB = (unsigned short*)(smem + 32768);   // 2 x [64*64]
  const int tid = threadIdx.x;
  const int lane = tid & 63;
  const int wid = tid >> 6;
  const int r = lane & 15, g = lane >> 4;
  const int wm = (wid >> 1) * 64, wn = (wid & 1) * 32;
  const int bm0 = blockIdx.y * BMT, bn0 = blockIdx.x * BNT;
  const int lrow = lane >> 3;
  const int lcol = ((lane & 7) ^ lrow) * 8;
  const unsigned short* Asrc = A + (size_t)(bm0 + wid * 32 + lrow) * K + lcol;
  const unsigned short* Bsrc = Bw + (size_t)(bn0 + wid * 16 + lrow) * K + lcol;
  const int fsw = (r & 7) << 4;
  f32x4 acc[MI][NI] = {};

  auto stage = [&](int k0, int buf) {
#pragma unroll
    for (int i = 0; i < 4; ++i)
      gload16(Asrc + (size_t)(i * 8) * K + k0, AlB + buf * 8192 + (wid * 32 + i * 8) * BK);
#pragma unroll
    for (int i = 0; i < 2; ++i)
      gload16(Bsrc + (size_t)(i * 8) * K + k0, BlB + buf * 4096 + (wid * 16 + i * 8) * BK);
  };

  stage(0, 0);
  __syncthreads();
  const int nt = K / BK;
  for (int t = 0; t < nt; ++t) {
    const int cur = t & 1;
    if (t + 1 < nt) stage((t + 1) * BK, cur ^ 1);
    const char* Ac = (const char*)(AlB + cur * 8192);
    const char* Bc = (const char*)(BlB + cur * 4096);
    bf16x8 af[MI][2], bfr[NI][2];
#pragma unroll
    for (int mi = 0; mi < MI; ++mi)
#pragma unroll
      for (int s = 0; s < 2; ++s)
        af[mi][s] = *reinterpret_cast<const bf16x8*>(
            Ac + (wm + mi * 16 + r) * 128 + ((s * 64 + g * 16) ^ fsw));
#pragma unroll
    for (int ni = 0; ni < NI; ++ni)
#pragma unroll
      for (int s = 0; s < 2; ++s)
        bfr[ni][s] = *reinterpret_cast<const bf16x8*>(
            Bc + (wn + ni * 16 + r) * 128 + ((s * 64 + g * 16) ^ fsw));
#pragma unroll
    for (int s = 0; s < 2; ++s)
#pragma unroll
      for (int mi = 0; mi < MI; ++mi)
#pragma unroll
        for (int ni = 0; ni < NI; ++ni)
          acc[mi][ni] = __builtin_amdgcn_mfma_f32_16x16x32_bf16(af[mi][s], bfr[ni][s],
                                                                acc[mi][ni], 0, 0, 0);
    __syncthreads();
  }
  // ---- fused epilogue ----
  float* Cl = (float*)smem;                                 // [128][65] f32 (33280 B)
  unsigned short* Vst = (unsigned short*)(smem + 33280);    // [64][128] bf16 (16 KB)
#pragma unroll
  for (int mi = 0; mi < MI; ++mi)
#pragma unroll
    for (int ni = 0; ni < NI; ++ni)
#pragma unroll
      for (int e = 0; e < 4; ++e)
        Cl[(wm + mi * 16 + g * 4 + e) * 65 + wn + ni * 16 + r] = acc[mi][ni][e];
  __syncthreads();
  const int head = blockIdx.x;
  const int trow = tid >> 1, half = tid & 1;
  const int tg = bm0 + trow;
  const int b = tg >> 11, t = tg & 2047;
  if (head < 20) {
    float r1[16], r2[16];
    float sq = 0.f;
#pragma unroll
    for (int i = 0; i < 16; ++i) {
      const int d = half * 16 + i;
      const float x1 = Cl[trow * 65 + d];
      const float x2 = Cl[trow * 65 + d + 32];
      const float c = cosb[t * 32 + d];
      const float s = sinb[t * 32 + d];
      r1[i] = x1 * c + x2 * s;
      r2[i] = x2 * c - x1 * s;
      sq += r1[i] * r1[i] + r2[i] * r2[i];
    }
    sq += __shfl_xor(sq, 1);
    // Q: 1.2 * (1/8 softmax scale) * log2(e); K: 1.2
    const float sc = rsqrtf(sq * (1.0f / 64.0f) + 1.1920929e-7f) *
                     ((head < 16) ? 0.21640425613334453f : 1.2f);
    unsigned short* dst = (head < 16)
        ? Qn + (((size_t)b * NH + head) * T_ + t) * HD
        : Kn + (((size_t)b * NKV + (head - 16)) * T_ + t) * HD;
#pragma unroll
    for (int i4 = 0; i4 < 4; ++i4) {
      ushort4 w1, w2;
      w1.x = f2bf(r1[i4 * 4 + 0] * sc); w1.y = f2bf(r1[i4 * 4 + 1] * sc);
      w1.z = f2bf(r1[i4 * 4 + 2] * sc); w1.w = f2bf(r1[i4 * 4 + 3] * sc);
      w2.x = f2bf(r2[i4 * 4 + 0] * sc); w2.y = f2bf(r2[i4 * 4 + 1] * sc);
      w2.z = f2bf(r2[i4 * 4 + 2] * sc); w2.w = f2bf(r2[i4 * 4 + 3] * sc);
      *reinterpret_cast<ushort4*>(dst + half * 16 + i4 * 4) = w1;
      *reinterpret_cast<ushort4*>(dst + half * 16 + 32 + i4 * 4) = w2;
    }
  } else {
    const int kv = head - 20;
    float dot = 0.f;
#pragma unroll
    for (int i = 0; i < 12; ++i) dot += x[(size_t)tg * C_ + i] * Wg[kv * 12 + i];
    const float gate = 3.0f / (1.0f + __expf(-dot));
    const float* vsrc = ve + (size_t)tg * (NKV * HD) + kv * HD;
#pragma unroll
    for (int i = 0; i < 32; ++i) {
      const int d = half * 32 + i;
      Vst[d * 128 + trow] = f2bf(Cl[trow * 65 + d] + gate * vsrc[d]);
    }
    __syncthreads();
    const int dd = tid >> 2, t0 = (tid & 3) * 32;
    unsigned short* vd = Vt + (((size_t)b * NKV + kv) * HD + dd) * T_ + (bm0 & 2047) + t0;
    const unsigned short* vs2 = Vst + dd * 128 + t0;
#pragma unroll
    for (int i = 0; i < 4; ++i)
      *reinterpret_cast<bf16x8*>(vd + i * 8) = *reinterpret_cast<const bf16x8*>(vs2 + i * 8);
  }
}

// ---------------- GEMM: C[M,N] = A[M,K] * B[N,K]^T  (bf16 in, f32 out) — gemm2 ----------
template <int BMT, int BNT, bool OUTBF>
__global__ __launch_bounds__(256) void gemm_bt(const unsigned short* __restrict__ A,
                                               const unsigned short* __restrict__ Bw,
                                               void* __restrict__ Cv, int M, int N, int K) {
  constexpr int MI = BMT / 32;
  constexpr int NI = BNT / 32;
  __shared__ unsigned short Al[2][BMT * BK];
  __shared__ unsigned short Bl[2][BNT * BK];
  const int tid = threadIdx.x;
  const int lane = tid & 63;
  const int wid = tid >> 6;
  const int r = lane & 15, g = lane >> 4;
  const int wm = (wid >> 1) * (BMT / 2), wn = (wid & 1) * (BNT / 2);
  const int bm0 = blockIdx.y * BMT, bn0 = blockIdx.x * BNT;
  const int lrow = lane >> 3;
  const int lcol = ((lane & 7) ^ lrow) * 8;
  const unsigned short* Asrc = A + (size_t)(bm0 + wid * (BMT / 4) + lrow) * K + lcol;
  const unsigned short* Bsrc = Bw + (size_t)(bn0 + wid * (BNT / 4) + lrow) * K + lcol;
  const int fsw = (r & 7) << 4;
  f32x4 acc[MI][NI] = {};

  auto stage = [&](int k0, int buf) {
#pragma unroll
    for (int i = 0; i < BMT / 32; ++i)
      gload16(Asrc + (size_t)(i * 8) * K + k0, Al[buf] + (wid * (BMT / 4) + i * 8) * BK);
#pragma unroll
    for (int i = 0; i < BNT / 32; ++i)
      gload16(Bsrc + (size_t)(i * 8) * K + k0, Bl[buf] + (wid * (BNT / 4) + i * 8) * BK);
  };

  stage(0, 0);
  __syncthreads();
  const int nt = K / BK;
  for (int t = 0; t < nt; ++t) {
    const int cur = t & 1;
    if (t + 1 < nt) stage((t + 1) * BK, cur ^ 1);
    const char* Ac = (const char*)Al[cur];
    const char* Bc = (const char*)Bl[cur];
    bf16x8 af[MI][2], bfr[NI][2];
#pragma unroll
    for (int mi = 0; mi < MI; ++mi)
#pragma unroll
      for (int s = 0; s < 2; ++s)
        af[mi][s] = *reinterpret_cast<const bf16x8*>(
            Ac + (wm + mi * 16 + r) * 128 + ((s * 64 + g * 16) ^ fsw));
#pragma unroll
    for (int ni = 0; ni < NI; ++ni)
#pragma unroll
      for (int s = 0; s < 2; ++s)
        bfr[ni][s] = *reinterpret_cast<const bf16x8*>(
            Bc + (wn + ni * 16 + r) * 128 + ((s * 64 + g * 16) ^ fsw));
#pragma unroll
    for (int s = 0; s < 2; ++s)
#pragma unroll
      for (int mi = 0; mi < MI; ++mi)
#pragma unroll
        for (int ni = 0; ni < NI; ++ni)
          acc[mi][ni] = __builtin_amdgcn_mfma_f32_16x16x32_bf16(af[mi][s], bfr[ni][s],
                                                                acc[mi][ni], 0, 0, 0);
    __syncthreads();
  }
#pragma unroll
  for (int mi = 0; mi < MI; ++mi)
#pragma unroll
    for (int ni = 0; ni < NI; ++ni) {
      const int row = bm0 + wm + mi * 16 + g * 4;
      const int col = bn0 + wn + ni * 16 + r;
#pragma unroll
      for (int e = 0; e < 4; ++e) {
        if (OUTBF)
          ((unsigned short*)Cv)[(size_t)(row + e) * N + col] = f2bf(acc[mi][ni][e]);
        else
          ((float*)Cv)[(size_t)(row + e) * N + col] = acc[mi][ni][e];
      }
    }
}

// ---------------- flash attention, sliding window, GQA ----------------
// EQUAL-WORK blocks (R13): pair {j,15-j} = 17 tile-units, singles qt>=16 = 17.
// Fixed-shift softmax: scores bounded |s|<=16.62 log2-units -> p=exp2(s-17), exact.
__global__ __launch_bounds__(256, 4) void attn_fwd(
    const unsigned short* __restrict__ Qn, const unsigned short* __restrict__ Kn,
    const unsigned short* __restrict__ Vt, unsigned short* __restrict__ Y,
    const int* __restrict__ wlp) {
  __shared__ unsigned short Kl[2][KVB * 64];
  __shared__ unsigned short Vl[2][64 * KVB];
  __shared__ unsigned short Pl[4][16 * 64];
  const int j = blockIdx.x, h = blockIdx.y, b = blockIdx.z;
  const int kvh = h >> 2;
  const int tid = threadIdx.x;
  const int wid = tid >> 6, lane = tid & 63;
  const int r = lane & 15, g = lane >> 4;
  const int wl = *wlp;
  const unsigned short* Kb = Kn + (size_t)(b * NKV + kvh) * T_ * HD;
  const unsigned short* Vb = Vt + (size_t)(b * NKV + kvh) * HD * T_;
  const int srow = tid >> 3;
  const int scolb = (tid & 7) * 16;
  const int sdst = srow * 128 + (scolb ^ ((srow & 7) << 4));
  const unsigned short* Ksrc0 = Kb + (size_t)srow * HD + (scolb >> 1);
  const unsigned short* Ksrc1 = Kb + (size_t)(srow + 32) * HD + (scolb >> 1);
  const unsigned short* Vsrc0 = Vb + (size_t)srow * T_ + (scolb >> 1);
  const unsigned short* Vsrc1 = Vb + (size_t)(srow + 32) * T_ + (scolb >> 1);
  char* Pwb = (char*)Pl[wid];
  const int swz = (r & 7) << 4;
  const int ksw = swz;
  const int nseg = (j < 8) ? 2 : 1;

  for (int seg = 0; seg < nseg; ++seg) {
    const int qt = (j < 8) ? (seg ? 15 - j : j) : j + 8;
    const int q0 = qt * 64;
    const int qs = q0 + wid * 16;
    const int q = qs + r;
    const unsigned short* Qb = Qn + ((size_t)(b * NH + h) * T_ + qs) * HD;
    const bf16x8 qf0 = *reinterpret_cast<const bf16x8*>(Qb + r * HD + g * 8);
    const bf16x8 qf1 = *reinterpret_cast<const bf16x8*>(Qb + r * HD + 32 + g * 8);
    float lrun = 0.f;
    f32x4 o[4] = {};
    int slo = q0 - wl; if (slo < 0) slo = 0;
    slo &= ~63;
    const int send = q0 + 63;

    bf16x8 ska, skb, sva, svb;
    ska = *reinterpret_cast<const bf16x8*>(Ksrc0 + (size_t)slo * HD);
    skb = *reinterpret_cast<const bf16x8*>(Ksrc1 + (size_t)slo * HD);
    sva = *reinterpret_cast<const bf16x8*>(Vsrc0 + slo);
    svb = *reinterpret_cast<const bf16x8*>(Vsrc1 + slo);
    {
      char* Kd = (char*)Kl[0]; char* Vd = (char*)Vl[0];
      *reinterpret_cast<bf16x8*>(Kd + sdst) = ska;
      *reinterpret_cast<bf16x8*>(Kd + 32 * 128 + sdst) = skb;
      *reinterpret_cast<bf16x8*>(Vd + sdst) = sva;
      *reinterpret_cast<bf16x8*>(Vd + 32 * 128 + sdst) = svb;
    }
    __syncthreads();

    int cur = 0;
    for (int sb = slo; sb <= send; sb += KVB) {
      const bool has_next = (sb + KVB <= send);
      if (has_next) {
        const int nb = sb + KVB;
        ska = *reinterpret_cast<const bf16x8*>(Ksrc0 + (size_t)nb * HD);
        skb = *reinterpret_cast<const bf16x8*>(Ksrc1 + (size_t)nb * HD);
        sva = *reinterpret_cast<const bf16x8*>(Vsrc0 + nb);
        svb = *reinterpret_cast<const bf16x8*>(Vsrc1 + nb);
      }
      {
        const char* Kc = (const char*)Kl[cur];
        const char* Vc = (const char*)Vl[cur];
        float sv[16];
        __builtin_amdgcn_s_setprio(1);
#pragma unroll
        for (int sub = 0; sub < 4; ++sub) {
          const int rowb = (sub * 16 + r) * 128;
          bf16x8 kf0 = *reinterpret_cast<const bf16x8*>(Kc + rowb + ((g * 16) ^ ksw));
          bf16x8 kf1 = *reinterpret_cast<const bf16x8*>(Kc + rowb + ((64 + g * 16) ^ ksw));
          f32x4 z = {};
          z = __builtin_amdgcn_mfma_f32_16x16x32_bf16(kf0, qf0, z, 0, 0, 0);
          z = __builtin_amdgcn_mfma_f32_16x16x32_bf16(kf1, qf1, z, 0, 0, 0);
#pragma unroll
          for (int e = 0; e < 4; ++e) sv[sub * 4 + e] = z[e];
        }
        __builtin_amdgcn_s_setprio(0);
        if (sb + 63 > qs || sb < qs + 15 - wl) {
#pragma unroll
          for (int i = 0; i < 16; ++i) {
            const int s_ = sb + (i >> 2) * 16 + g * 4 + (i & 3);
            const bool ok = (unsigned)(q - s_) <= (unsigned)wl;
            sv[i] = ok ? sv[i] : -__builtin_inff();
          }
        }
        float pe[16];
        float ps = 0.f;
#pragma unroll
        for (int i = 0; i < 16; ++i) {
          pe[i] = exp2f(sv[i] - 17.0f);
          ps += pe[i];
        }
        lrun += ps;
#pragma unroll
        for (int sub = 0; sub < 4; ++sub) {
          unsigned w2[2];
          w2[0] = cvtpk(pe[sub * 4 + 0], pe[sub * 4 + 1]);
          w2[1] = cvtpk(pe[sub * 4 + 2], pe[sub * 4 + 3]);
          bf16x4 w;
          __builtin_memcpy(&w, w2, 8);
          *reinterpret_cast<bf16x4*>(Pwb + ((r * 128 + sub * 32 + g * 8) ^ swz)) = w;
        }
        asm volatile("s_waitcnt lgkmcnt(0)" ::: "memory");
        __builtin_amdgcn_s_setprio(1);
#pragma unroll
        for (int c = 0; c < 2; ++c) {
          const bf16x8 pf = *reinterpret_cast<const bf16x8*>(Pwb + ((r * 128 + c * 64 + g * 16) ^ swz));
#pragma unroll
          for (int dt = 0; dt < 4; ++dt) {
            const int vrow = (dt * 16 + r) * 128;
            const bf16x8 vf = *reinterpret_cast<const bf16x8*>(Vc + vrow + ((c * 64 + g * 16) ^ ksw));
            o[dt] = __builtin_amdgcn_mfma_f32_16x16x32_bf16(vf, pf, o[dt], 0, 0, 0);
          }
        }
        __builtin_amdgcn_s_setprio(0);
      }
      if (has_next) {
        char* Kd = (char*)Kl[cur ^ 1]; char* Vd = (char*)Vl[cur ^ 1];
        *reinterpret_cast<bf16x8*>(Kd + sdst) = ska;
        *reinterpret_cast<bf16x8*>(Kd + 32 * 128 + sdst) = skb;
        *reinterpret_cast<bf16x8*>(Vd + sdst) = sva;
        *reinterpret_cast<bf16x8*>(Vd + 32 * 128 + sdst) = svb;
      }
      __syncthreads();
      cur ^= 1;
    }
    lrun += __shfl_xor(lrun, 16);
    lrun += __shfl_xor(lrun, 32);
    const float inv = 1.0f / lrun;
    unsigned short* Yb = Y + ((size_t)(b * T_) + qs + r) * (NH * HD) + h * HD;
#pragma unroll
    for (int dt = 0; dt < 4; ++dt)
#pragma unroll
      for (int e = 0; e < 4; ++e)
        Yb[dt * 16 + g * 4 + e] = f2bf(o[dt][e] * inv);
  }
}

extern "C" void kernel_launch(void* const* d_in, const int* in_sizes, int n_in,
                              void* d_out, int out_size, void* d_ws, size_t ws_size,
                              hipStream_t stream) {
  const float* x    = (const float*)d_in[0];
  const float* ve   = (const float*)d_in[1];
  const float* cosb = (const float*)d_in[2];
  const float* sinb = (const float*)d_in[3];
  const float* Wq   = (const float*)d_in[4];
  const float* Wk   = (const float*)d_in[5];
  const float* Wv   = (const float*)d_in[6];
  const float* Wo   = (const float*)d_in[7];
  const float* Wg   = (const float*)d_in[8];
  const int*   wlp  = (const int*)d_in[9];

  char* ws = (char*)d_ws;
  unsigned short* xb    = (unsigned short*)ws; ws += (size_t)4096 * 1024 * 2;
  unsigned short* wqkvb = (unsigned short*)ws; ws += (size_t)1536 * 1024 * 2;
  unsigned short* wob   = (unsigned short*)ws; ws += (size_t)1024 * 1024 * 2;
  unsigned short* Qn    = (unsigned short*)ws; ws += (size_t)B_ * NH * T_ * HD * 2;
  unsigned short* Kn    = (unsigned short*)ws; ws += (size_t)B_ * NKV * T_ * HD * 2;
  unsigned short* Vt    = (unsigned short*)ws; ws += (size_t)B_ * NKV * HD * T_ * 2;
  unsigned short* yb    = (unsigned short*)ws; ws += (size_t)4096 * 1024 * 2;

  conv_all<<<dim3(2048), dim3(256), 0, stream>>>(x, Wq, Wk, Wv, Wo, xb, wqkvb, wob);

  gemm_qkv<<<dim3(NQKV / 64, 4096 / 128), dim3(256), 0, stream>>>(
      xb, wqkvb, x, ve, cosb, sinb, Wg, Qn, Kn, Vt);

  attn_fwd<<<dim3(24, NH, B_), dim3(256), 0, stream>>>(Qn, Kn, Vt, yb, wlp);

  gemm_bt<128, 64, false><<<dim3(1024 / 64, 4096 / 128), dim3(256), 0, stream>>>(
      yb, wob, d_out, 4096, 1024, 1024);
}